// Round 15
// baseline (196.584 us; speedup 1.0000x reference)
//
#include <hip/hip_runtime.h>
#include <stdint.h>

// SAGE_876173328847: 2-layer bipartite SAGEConv (mean agg) + log_softmax.
// N0=200000, N1=100000, N2=20000, E1=1.6M, E2=320K, D_IN=128, D_H=256, D_OUT=64.
//
// R1: atomic scatter -> CSR build + gather (3309 -> 667 us).
// R2/R3: bf16 heavy path + MFMA GEMMs (667 -> 547 us).
// R4: fused mega-kernel, h1 lives only in LDS (547 -> 472 us).
// R7: scan-based multi-split CSR build, zero global atomics (-> 366 us).
// R8: spill-free mega (-> 347). R9: launch fusion 22->14 (-> 285).
// R11: 32x32x16 MFMA 32-rows/wave fused mega (-> 264).
// R12: fragment-order W + LDS staging (-> 212). R13: gather MLP + fusions (-> 196).
// R14: wave-per-dst gather1, uint2 loads (-> 191.9; gather1 62 us, request-bound).
// R15: gather1 uint4 loads (16 lanes/row, 4-edge subgroups, 4x 1KB wave-loads
//      in flight); csr_bdeg+csr_scan_local fused. 11 -> 10 dispatches.

#define CN0 200000
#define CN1 100000
#define CN2 20000
#define CE1 1600000
#define CE2 320000
#define CD_IN 128
#define CD_H 256
#define CD_OUT 64

// multi-split geometry: bucket = dst >> 9 (512 dsts per bucket)
#define NBK1 196          // ceil(N1/512)
#define NBK2 40           // ceil(N2/512)
#define G1 256
#define G2 64
#define CHUNK1 6250       // E1 / G1
#define CHUNK2 5000       // E2 / G2

typedef __bf16 bf16x8 __attribute__((ext_vector_type(8)));
typedef float f32x4 __attribute__((ext_vector_type(4)));
typedef float f32x16 __attribute__((ext_vector_type(16)));
typedef uint16_t u16x4 __attribute__((ext_vector_type(4)));

__device__ inline uint16_t f2bf(float f) {
  uint32_t u = __float_as_uint(f);
  return (uint16_t)((u + 0x7fffu + ((u >> 16) & 1u)) >> 16);
}
__device__ inline float blo(uint32_t v) { return __uint_as_float(v << 16); }
__device__ inline float bhi(uint32_t v) { return __uint_as_float(v & 0xffff0000u); }

// ---- fused: x convert (25000 blk) + weight frags (48 blk) + csr_count (320 blk) ----
// wfragG : [8 n][16 t][64 lane][8] ; value = Wcat[n*32+(lane&31)][t*16+(lane>>5)*8+e]
// w2fragG: [4 j][16 tt][64 lane][8]; value = W2cat[j*32+(lane&31)][tt*16+(lane>>5)*8+e]
__global__ __launch_bounds__(256) void cvt_count(
    const float* __restrict__ x, const float* __restrict__ Wl1,
    const float* __restrict__ Wr1, const float* __restrict__ Wl2,
    const float* __restrict__ Wr2, const int* __restrict__ dst1,
    const int* __restrict__ dst2, uint16_t* __restrict__ x_bf,
    uint16_t* __restrict__ wfragG, uint16_t* __restrict__ w2fragG,
    int* __restrict__ H1, int* __restrict__ H2) {
  __shared__ int hist[256];
  int blk = blockIdx.x;
  if (blk < 25000) {
    int i = blk * 256 + threadIdx.x;      // < 6,400,000 exactly
    float4 v = reinterpret_cast<const float4*>(x)[i];
    u16x4 o = {f2bf(v.x), f2bf(v.y), f2bf(v.z), f2bf(v.w)};
    reinterpret_cast<u16x4*>(x_bf)[i] = o;
    return;
  }
  if (blk < 25048) {
    int c = (blk - 25000) * 256 + threadIdx.x;   // 0..12287
    uint16_t o[8];
    if (c < 8192) {
      int lane = c & 63, t = (c >> 6) & 15, n = c >> 10;
      int row = n * 32 + (lane & 31);
      int kk = t * 16 + (lane >> 5) * 8;
      const float* srcp = (kk < 128) ? (Wl1 + (size_t)row * 128 + kk)
                                     : (Wr1 + (size_t)row * 128 + (kk - 128));
#pragma unroll
      for (int e = 0; e < 8; ++e) o[e] = f2bf(srcp[e]);
      *reinterpret_cast<int4*>(wfragG + (size_t)c * 8) = *reinterpret_cast<int4*>(o);
    } else {
      int cc = c - 8192;                    // 0..4095
      int lane = cc & 63, tt = (cc >> 6) & 15, j = cc >> 10;
      int row = j * 32 + (lane & 31);
      int kk = tt * 16 + (lane >> 5) * 8;
      const float* srcp = (row < 64) ? (Wl2 + (size_t)row * 256 + kk)
                                     : (Wr2 + (size_t)(row - 64) * 256 + kk);
#pragma unroll
      for (int e = 0; e < 8; ++e) o[e] = f2bf(srcp[e]);
      *reinterpret_cast<int4*>(w2fragG + (size_t)cc * 8) = *reinterpret_cast<int4*>(o);
    }
    return;
  }
  // ---- histogram chunk ----
  int g = blk - 25048, t = threadIdx.x;
  const int* dst; int* H; int E, nb, chunk;
  if (g < G1) { dst = dst1; H = H1; E = CE1; nb = NBK1; chunk = CHUNK1; }
  else { g -= G1; dst = dst2; H = H2; E = CE2; nb = NBK2; chunk = CHUNK2; }
  hist[t] = 0;
  __syncthreads();
  int e0 = g * chunk, e1 = min(e0 + chunk, E);
  for (int e = e0 + t; e < e1; e += 256) atomicAdd(&hist[dst[e] >> 9], 1);
  __syncthreads();
  if (t < nb) H[g * nb + t] = hist[t];
}

// ---------------- dual-layer scan-based multi-split ----------------
__global__ __launch_bounds__(256) void csr_scan(
    int* __restrict__ H1, int* __restrict__ H2,
    int* __restrict__ T1, int* __restrict__ T2) {
  __shared__ int sm[256];
  int b = blockIdx.x, t = threadIdx.x;
  int* H; int* T; int nb, G;
  if (b < NBK1) { H = H1; T = T1; nb = NBK1; G = G1; }
  else { b -= NBK1; H = H2; T = T2; nb = NBK2; G = G2; }
  int v = (t < G) ? H[t * nb + b] : 0;
  sm[t] = v;
  __syncthreads();
#pragma unroll
  for (int off = 1; off < 256; off <<= 1) {
    int u = (t >= off) ? sm[t - off] : 0;
    __syncthreads();
    sm[t] += u;
    __syncthreads();
  }
  if (t < G) H[t * nb + b] = sm[t] - v;  // exclusive over chunks
  if (t == 255) T[b] = sm[255];          // bucket total
}

__global__ __launch_bounds__(256) void csr_base(
    const int* __restrict__ T1, const int* __restrict__ T2,
    int* __restrict__ Bb1, int* __restrict__ Bb2) {
  __shared__ int sm[256];
  int t = threadIdx.x;
  const int* T; int* Bb; int nb;
  if (blockIdx.x == 0) { T = T1; Bb = Bb1; nb = NBK1; }
  else { T = T2; Bb = Bb2; nb = NBK2; }
  int v = (t < nb) ? T[t] : 0;
  sm[t] = v;
  __syncthreads();
#pragma unroll
  for (int off = 1; off < 256; off <<= 1) {
    int u = (t >= off) ? sm[t - off] : 0;
    __syncthreads();
    sm[t] += u;
    __syncthreads();
  }
  if (t < nb) Bb[t] = sm[t] - v;
}

__global__ __launch_bounds__(256) void csr_place(
    const int* __restrict__ src1, const int* __restrict__ dst1,
    const int* __restrict__ src2, const int* __restrict__ dst2,
    const int* __restrict__ H1, const int* __restrict__ H2,
    const int* __restrict__ Bb1, const int* __restrict__ Bb2,
    uint32_t* __restrict__ pairs1, uint32_t* __restrict__ pairs2) {
  __shared__ int curs[256];
  int g = blockIdx.x, t = threadIdx.x;
  const int* src; const int* dst; const int* H; const int* Bb;
  uint32_t* pairs; int E, nb, chunk;
  if (g < G1) { src = src1; dst = dst1; H = H1; Bb = Bb1; pairs = pairs1;
                E = CE1; nb = NBK1; chunk = CHUNK1; }
  else { g -= G1; src = src2; dst = dst2; H = H2; Bb = Bb2; pairs = pairs2;
         E = CE2; nb = NBK2; chunk = CHUNK2; }
  if (t < nb) curs[t] = Bb[t] + H[g * nb + t];
  __syncthreads();
  int e0 = g * chunk, e1 = min(e0 + chunk, E);
  for (int e = e0 + t; e < e1; e += 256) {
    int d = dst[e];
    int b = d >> 9;
    int p = atomicAdd(&curs[b], 1);
    pairs[p] = (uint32_t)src[e] | ((uint32_t)(d & 511) << 18);
  }
}

// ---- FUSED bdeg + scan_local: per-bucket degree count (LDS), per-block
// exclusive scan of the 512 degrees, writes deg, R (bucket-local excl), part.
__global__ __launch_bounds__(256) void csr_bdeg_scan(
    const uint32_t* __restrict__ pairs1, const uint32_t* __restrict__ pairs2,
    const int* __restrict__ Bb1, const int* __restrict__ Bb2,
    const int* __restrict__ T1, const int* __restrict__ T2,
    int* __restrict__ deg1, int* __restrict__ deg2,
    int* __restrict__ R1, int* __restrict__ R2,
    int* __restrict__ part1, int* __restrict__ part2) {
  __shared__ int cnt[512];
  __shared__ int sm[256];
  int b = blockIdx.x, t = threadIdx.x;
  const uint32_t* pairs; const int* Bb; const int* T;
  int* deg; int* R; int* part; int ndst;
  if (b < NBK1) { pairs = pairs1; Bb = Bb1; T = T1; deg = deg1; R = R1;
                  part = part1; ndst = CN1; }
  else { b -= NBK1; pairs = pairs2; Bb = Bb2; T = T2; deg = deg2; R = R2;
         part = part2; ndst = CN2; }
  cnt[t] = 0;
  cnt[t + 256] = 0;
  __syncthreads();
  int s0 = Bb[b], n = T[b];
  for (int i = t; i < n; i += 256) atomicAdd(&cnt[pairs[s0 + i] >> 18], 1);
  __syncthreads();
  int d0 = b << 9;
  int a = cnt[2 * t], c = cnt[2 * t + 1];
  int i0 = d0 + 2 * t, i1 = d0 + 2 * t + 1;
  if (i0 < ndst) deg[i0] = a;
  if (i1 < ndst) deg[i1] = c;
  int s = a + c;
  sm[t] = s;
  __syncthreads();
#pragma unroll
  for (int off = 1; off < 256; off <<= 1) {
    int u = (t >= off) ? sm[t - off] : 0;
    __syncthreads();
    sm[t] += u;
    __syncthreads();
  }
  int excl = sm[t] - s;
  if (i0 < ndst) R[i0] = excl;
  if (i1 < ndst) R[i1] = excl + a;
  if (t == 255) part[b] = sm[255];
}

__global__ __launch_bounds__(256) void csr_scan_part(
    int* __restrict__ part1, int* __restrict__ part2) {
  __shared__ int sm[256];
  int t = threadIdx.x;
  int* part; int B;
  if (blockIdx.x == 0) { part = part1; B = NBK1; }
  else { part = part2; B = NBK2; }
  int v = (t < B) ? part[t] : 0;
  sm[t] = v;
  __syncthreads();
#pragma unroll
  for (int off = 1; off < 256; off <<= 1) {
    int u = (t >= off) ? sm[t - off] : 0;
    __syncthreads();
    sm[t] += u;
    __syncthreads();
  }
  if (t < B) part[t] = sm[t] - v;
}

// bplace with addback folded in: final offset = R[dd] + part[bucket]
__global__ __launch_bounds__(256) void csr_bplace(
    const uint32_t* __restrict__ pairs1, const uint32_t* __restrict__ pairs2,
    const int* __restrict__ Bb1, const int* __restrict__ Bb2,
    const int* __restrict__ T1, const int* __restrict__ T2,
    const int* __restrict__ R1, const int* __restrict__ R2,
    const int* __restrict__ part1, const int* __restrict__ part2,
    int* __restrict__ esrc1, int* __restrict__ esrc2) {
  __shared__ int curs[512];
  int b = blockIdx.x, t = threadIdx.x;
  const uint32_t* pairs; const int* Bb; const int* T; const int* R;
  const int* part; int* esrc; int ndst;
  if (b < NBK1) { pairs = pairs1; Bb = Bb1; T = T1; R = R1; part = part1;
                  esrc = esrc1; ndst = CN1; }
  else { b -= NBK1; pairs = pairs2; Bb = Bb2; T = T2; R = R2; part = part2;
         esrc = esrc2; ndst = CN2; }
  int d0 = b << 9;
  int pb = part[b];
#pragma unroll
  for (int j = 0; j < 2; ++j) {
    int dd = d0 + t + j * 256;
    curs[t + j * 256] = (dd < ndst) ? R[dd] + pb : 0;
  }
  __syncthreads();
  int s0 = Bb[b], n = T[b];
  for (int i = t; i < n; i += 256) {
    uint32_t pk = pairs[s0 + i];
    int p = atomicAdd(&curs[pk >> 18], 1);
    esrc[p] = (int)(pk & 0x3FFFFu);
  }
}

// ------- gather-mean layer 1 (R15): one dst per WAVE, uint4 row loads,
// 16 lanes/row, 4 edge-subgroups, 16-edge main loop (4x 1KB wave-loads) -------
__global__ __launch_bounds__(256) void sage_gather1(
    const uint16_t* __restrict__ xbf, const int* __restrict__ esrc,
    const int* __restrict__ R, const int* __restrict__ part,
    const int* __restrict__ deg, uint16_t* __restrict__ agg) {
  const int d = __builtin_amdgcn_readfirstlane(blockIdx.x * 4 + (threadIdx.x >> 6));
  const int lane = threadIdx.x & 63;
  const int cc = lane & 15;    // 16B chunk within row (cols 8cc..8cc+7)
  const int h = lane >> 4;     // 0..3 edge subgroup
  const int start = __builtin_amdgcn_readfirstlane(R[d] + part[d >> 9]);
  const int n = __builtin_amdgcn_readfirstlane(deg[d]);
  const uint4* xw = reinterpret_cast<const uint4*>(xbf);   // row = 16 uint4
  float a0 = 0.f, a1 = 0.f, a2 = 0.f, a3 = 0.f;
  float a4 = 0.f, a5 = 0.f, a6 = 0.f, a7 = 0.f;
  float c0 = 0.f, c1 = 0.f, c2 = 0.f, c3 = 0.f;
  float c4 = 0.f, c5 = 0.f, c6 = 0.f, c7 = 0.f;
  int i = 0;
  for (; i + 16 <= n; i += 16) {
    int s0 = esrc[start + i + h];
    int s1 = esrc[start + i + 4 + h];
    int s2 = esrc[start + i + 8 + h];
    int s3 = esrc[start + i + 12 + h];
    uint4 v0 = xw[(uint32_t)s0 * 16u + cc];
    uint4 v1 = xw[(uint32_t)s1 * 16u + cc];
    uint4 v2 = xw[(uint32_t)s2 * 16u + cc];
    uint4 v3 = xw[(uint32_t)s3 * 16u + cc];
    a0 += blo(v0.x) + blo(v1.x); a1 += bhi(v0.x) + bhi(v1.x);
    a2 += blo(v0.y) + blo(v1.y); a3 += bhi(v0.y) + bhi(v1.y);
    a4 += blo(v0.z) + blo(v1.z); a5 += bhi(v0.z) + bhi(v1.z);
    a6 += blo(v0.w) + blo(v1.w); a7 += bhi(v0.w) + bhi(v1.w);
    c0 += blo(v2.x) + blo(v3.x); c1 += bhi(v2.x) + bhi(v3.x);
    c2 += blo(v2.y) + blo(v3.y); c3 += bhi(v2.y) + bhi(v3.y);
    c4 += blo(v2.z) + blo(v3.z); c5 += bhi(v2.z) + bhi(v3.z);
    c6 += blo(v2.w) + blo(v3.w); c7 += bhi(v2.w) + bhi(v3.w);
  }
  for (; i + 4 <= n; i += 4) {
    int s0 = esrc[start + i + h];
    uint4 v = xw[(uint32_t)s0 * 16u + cc];
    a0 += blo(v.x); a1 += bhi(v.x); a2 += blo(v.y); a3 += bhi(v.y);
    a4 += blo(v.z); a5 += bhi(v.z); a6 += blo(v.w); a7 += bhi(v.w);
  }
  if (i < n && h < n - i) {
    int s0 = esrc[start + i + h];
    uint4 v = xw[(uint32_t)s0 * 16u + cc];
    a0 += blo(v.x); a1 += bhi(v.x); a2 += blo(v.y); a3 += bhi(v.y);
    a4 += blo(v.z); a5 += bhi(v.z); a6 += blo(v.w); a7 += bhi(v.w);
  }
  a0 += c0; a1 += c1; a2 += c2; a3 += c3;
  a4 += c4; a5 += c5; a6 += c6; a7 += c7;
  // reduce across the 4 subgroups (lanes 16 and 32 apart)
  a0 += __shfl_xor(a0, 16); a0 += __shfl_xor(a0, 32);
  a1 += __shfl_xor(a1, 16); a1 += __shfl_xor(a1, 32);
  a2 += __shfl_xor(a2, 16); a2 += __shfl_xor(a2, 32);
  a3 += __shfl_xor(a3, 16); a3 += __shfl_xor(a3, 32);
  a4 += __shfl_xor(a4, 16); a4 += __shfl_xor(a4, 32);
  a5 += __shfl_xor(a5, 16); a5 += __shfl_xor(a5, 32);
  a6 += __shfl_xor(a6, 16); a6 += __shfl_xor(a6, 32);
  a7 += __shfl_xor(a7, 16); a7 += __shfl_xor(a7, 32);
  if (lane < 16) {
    float inv = 1.0f / fmaxf((float)n, 1.0f);
    uint4 o;
    o.x = (uint32_t)f2bf(a0 * inv) | ((uint32_t)f2bf(a1 * inv) << 16);
    o.y = (uint32_t)f2bf(a2 * inv) | ((uint32_t)f2bf(a3 * inv) << 16);
    o.z = (uint32_t)f2bf(a4 * inv) | ((uint32_t)f2bf(a5 * inv) << 16);
    o.w = (uint32_t)f2bf(a6 * inv) | ((uint32_t)f2bf(a7 * inv) << 16);
    reinterpret_cast<uint4*>(agg)[(size_t)d * 16 + cc] = o;
  }
}

// ------- FUSED gather-mean layer 2 + log_softmax finalize -------
__global__ __launch_bounds__(256) void sage_gather2_fin(
    const uint16_t* __restrict__ t2, const int* __restrict__ esrc,
    const int* __restrict__ R, const int* __restrict__ part,
    const int* __restrict__ deg, const float* __restrict__ b2,
    float* __restrict__ out) {
  int d = blockIdx.x * 8 + (threadIdx.x >> 5);
  int c = threadIdx.x & 31;
  if (d >= CN2) return;
  int start = R[d] + part[d >> 9], n = deg[d];
  const uint32_t* tw = reinterpret_cast<const uint32_t*>(t2);
  float a0 = 0.f, a1 = 0.f, b0 = 0.f, b1 = 0.f;
  int i = 0;
  for (; i + 8 <= n; i += 8) {
    int s0 = esrc[start + i + 0], s1 = esrc[start + i + 1];
    int s2 = esrc[start + i + 2], s3 = esrc[start + i + 3];
    int s4 = esrc[start + i + 4], s5 = esrc[start + i + 5];
    int s6 = esrc[start + i + 6], s7 = esrc[start + i + 7];
    uint32_t v0 = tw[(size_t)s0 * 32 + c], v1 = tw[(size_t)s1 * 32 + c];
    uint32_t v2 = tw[(size_t)s2 * 32 + c], v3 = tw[(size_t)s3 * 32 + c];
    uint32_t v4 = tw[(size_t)s4 * 32 + c], v5 = tw[(size_t)s5 * 32 + c];
    uint32_t v6 = tw[(size_t)s6 * 32 + c], v7 = tw[(size_t)s7 * 32 + c];
    a0 += (blo(v0) + blo(v1)) + (blo(v2) + blo(v3));
    b0 += (blo(v4) + blo(v5)) + (blo(v6) + blo(v7));
    a1 += (bhi(v0) + bhi(v1)) + (bhi(v2) + bhi(v3));
    b1 += (bhi(v4) + bhi(v5)) + (bhi(v6) + bhi(v7));
  }
  for (; i + 2 <= n; i += 2) {
    int s0 = esrc[start + i + 0], s1 = esrc[start + i + 1];
    uint32_t v0 = tw[(size_t)s0 * 32 + c], v1 = tw[(size_t)s1 * 32 + c];
    a0 += blo(v0) + blo(v1);
    a1 += bhi(v0) + bhi(v1);
  }
  if (i < n) {
    uint32_t v = tw[(size_t)esrc[start + i] * 32 + c];
    a0 += blo(v);
    a1 += bhi(v);
  }
  a0 += b0; a1 += b1;
  float inv = 1.0f / fmaxf((float)n, 1.0f);

  float2 ov = reinterpret_cast<const float2*>(out)[(size_t)d * 32 + c];
  float2 bb = reinterpret_cast<const float2*>(b2)[c];
  float v0 = ov.x + a0 * inv + bb.x;
  float v1 = ov.y + a1 * inv + bb.y;
  float m = fmaxf(v0, v1);
#pragma unroll
  for (int off = 16; off > 0; off >>= 1) m = fmaxf(m, __shfl_xor(m, off));
  float s = expf(v0 - m) + expf(v1 - m);
#pragma unroll
  for (int off = 16; off > 0; off >>= 1) s += __shfl_xor(s, off);
  float lg = logf(s);
  float2 r;
  r.x = v0 - m - lg;
  r.y = v1 - m - lg;
  reinterpret_cast<float2*>(out)[(size_t)d * 32 + c] = r;
}

// ---------------- MEGA kernel (R12: LDS-staged fragment-order W) ----------------
__global__ __launch_bounds__(256, 2) void sage_mega(
    const uint16_t* __restrict__ agg, const uint16_t* __restrict__ xbf,
    const uint16_t* __restrict__ wfragG, const uint16_t* __restrict__ w2fragG,
    const float* __restrict__ bias, uint16_t* __restrict__ t2,
    float* __restrict__ outp) {
  __shared__ uint16_t wfrag[32768];       // 64 KB: 64 chunks x 512 shorts
  __shared__ uint16_t h1t[4 * 32 * 40];   // 10240 B; per-wave 32x40 transpose tile
  const int tid = threadIdx.x;
  const int w = tid >> 6;
  const int lane = tid & 63;
  const int lcol = lane & 31;             // A-row / B-col / C-col
  const int hi = lane >> 5;               // k-half (frags) / row +4 (C)
  const int row0 = blockIdx.x * 128 + w * 32;
  uint16_t* hw = &h1t[w * (32 * 40)];

  // A fragments: 16 k-tiles of K=16 from [agg | x]; lane: row=lcol, k=hi*8..+7
  int arow = row0 + lcol;
  arow = arow < CN1 ? arow : CN1 - 1;
  bf16x8 afr[16];
#pragma unroll
  for (int t = 0; t < 16; ++t) {
    const uint16_t* Asrc = (t < 8) ? agg : xbf;
    const int koff = (t < 8) ? t * 16 : t * 16 - 128;
    afr[t] = *reinterpret_cast<const bf16x8*>(
        Asrc + (size_t)arow * CD_IN + koff + hi * 8);
  }

  const bool do_out = (row0 < CN2);       // CN2 % 32 == 0 -> wave-uniform
  bf16x8 a2[16];                          // h1 A-frags, filled per n (static idx)

#pragma unroll
  for (int h = 0; h < 2; ++h) {
    // stage half h of W1 fragments: 64 chunks x 1 KB, 16 per wave, coalesced
#pragma unroll
    for (int i = 0; i < 16; ++i) {
      int cc = i * 4 + w;
      int4 v = *reinterpret_cast<const int4*>(
          wfragG + (size_t)(h * 64 + cc) * 512 + lane * 8);
      *reinterpret_cast<int4*>(&wfrag[cc * 512 + lane * 8]) = v;
    }
    __syncthreads();
#pragma unroll
    for (int nn = 0; nn < 4; ++nn) {
      const int n = h * 4 + nn;
      const float bb = bias[n * 32 + lcol];
      f32x16 p0 = (f32x16)0.0f, p1 = (f32x16)0.0f;
#pragma unroll
      for (int t = 0; t < 16; t += 2) {
        bf16x8 b0 = *reinterpret_cast<const bf16x8*>(
            &wfrag[((nn * 16 + t) * 64 + lane) * 8]);
        bf16x8 b1 = *reinterpret_cast<const bf16x8*>(
            &wfrag[((nn * 16 + t + 1) * 64 + lane) * 8]);
        p0 = __builtin_amdgcn_mfma_f32_32x32x16_bf16(afr[t], b0, p0, 0, 0, 0);
        p1 = __builtin_amdgcn_mfma_f32_32x32x16_bf16(afr[t + 1], b1, p1, 0, 0, 0);
      }
      // bias + relu -> bf16 -> per-wave LDS transpose tile (C layout m74/m101)
#pragma unroll
      for (int r = 0; r < 16; ++r) {
        float v = fmaxf(p0[r] + p1[r] + bb, 0.0f);
        int R = (r & 3) + 8 * (r >> 2) + 4 * hi;
        hw[R * 40 + lcol] = f2bf(v);
      }
      // read back as phase-2 A-frags (k = n*32 + {0..15, 16..31})
      a2[n * 2 + 0] = *reinterpret_cast<const bf16x8*>(&hw[lcol * 40 + hi * 8]);
      a2[n * 2 + 1] = *reinterpret_cast<const bf16x8*>(&hw[lcol * 40 + 16 + hi * 8]);
    }
    __syncthreads();   // all waves done reading this half before overwrite
  }

  // stage w2 fragments (64 KB) into the same buffer
#pragma unroll
  for (int i = 0; i < 16; ++i) {
    int cc = i * 4 + w;
    int4 v = *reinterpret_cast<const int4*>(
        w2fragG + (size_t)cc * 512 + lane * 8);
    *reinterpret_cast<int4*>(&wfrag[cc * 512 + lane * 8]) = v;
  }
  __syncthreads();

  // ---- phase 2: jp=0 -> t2 cols (j=0,1); jp=1 -> out cols (j=2,3) ----
#pragma unroll
  for (int jp = 0; jp < 2; ++jp) {
    if (jp == 1 && !do_out) break;
    const int jA = jp * 2, jB = jp * 2 + 1;
    f32x16 aA = (f32x16)0.0f, aB = (f32x16)0.0f;
#pragma unroll
    for (int s = 0; s < 8; ++s) {
      bf16x8 c0A = *reinterpret_cast<const bf16x8*>(
          &wfrag[((jA * 16 + s * 2) * 64 + lane) * 8]);
      bf16x8 c1A = *reinterpret_cast<const bf16x8*>(
          &wfrag[((jA * 16 + s * 2 + 1) * 64 + lane) * 8]);
      bf16x8 c0B = *reinterpret_cast<const bf16x8*>(
          &wfrag[((jB * 16 + s * 2) * 64 + lane) * 8]);
      bf16x8 c1B = *reinterpret_cast<const bf16x8*>(
          &wfrag[((jB * 16 + s * 2 + 1) * 64 + lane) * 8]);
      aA = __builtin_amdgcn_mfma_f32_32x32x16_bf16(a2[s * 2], c0A, aA, 0, 0, 0);
      aB = __builtin_amdgcn_mfma_f32_32x32x16_bf16(a2[s * 2], c0B, aB, 0, 0, 0);
      aA = __builtin_amdgcn_mfma_f32_32x32x16_bf16(a2[s * 2 + 1], c1A, aA, 0, 0, 0);
      aB = __builtin_amdgcn_mfma_f32_32x32x16_bf16(a2[s * 2 + 1], c1B, aB, 0, 0, 0);
    }
    if (jp == 0) {
#pragma unroll
      for (int r = 0; r < 16; ++r) {
        int R = (r & 3) + 8 * (r >> 2) + 4 * hi;
        int rg = row0 + R;
        if (rg < CN1) {
          t2[(size_t)rg * 64 + lcol] = f2bf(aA[r]);
          t2[(size_t)rg * 64 + 32 + lcol] = f2bf(aB[r]);
        }
      }
    } else {
#pragma unroll
      for (int r = 0; r < 16; ++r) {
        int R = (r & 3) + 8 * (r >> 2) + 4 * hi;
        int rg = row0 + R;
        outp[(size_t)rg * 64 + lcol] = aA[r];
        outp[(size_t)rg * 64 + 32 + lcol] = aB[r];
      }
    }
  }
}

extern "C" void kernel_launch(void* const* d_in, const int* in_sizes, int n_in,
                              void* d_out, int out_size, void* d_ws, size_t ws_size,
                              hipStream_t stream) {
  const float* x    = (const float*)d_in[0];
  const int* src1   = (const int*)d_in[1];
  const int* dst1   = (const int*)d_in[2];
  const int* src2   = (const int*)d_in[3];
  const int* dst2   = (const int*)d_in[4];
  const float* W_l1 = (const float*)d_in[5];
  const float* b_l1 = (const float*)d_in[6];
  const float* W_r1 = (const float*)d_in[7];
  const float* W_l2 = (const float*)d_in[8];
  const float* b_l2 = (const float*)d_in[9];
  const float* W_r2 = (const float*)d_in[10];
  float* out = (float*)d_out;
  char* base = (char*)d_ws;

  // ---- workspace layout (bytes), ~111.5 MB ----
  uint16_t* x_bf  = (uint16_t*)base;                       // 51.2 MB
  uint16_t* t2_bf = (uint16_t*)(base + 51200000);          // 12.8 MB
  uint32_t* pairs1= (uint32_t*)(base + 64000000);          // 6.4 MB (E1*4)
  uint32_t* pairs2= (uint32_t*)(base + 70400000);          // 1.28 MB (E2*4)
  uint16_t* agg_bf= (uint16_t*)(base + 71680000);          // 25.6 MB
  int* deg1 = (int*)(base + 102400000);                    // 400 KB
  int* R1   = (int*)(base + 102800000);                    // 400 KB
  int* esrc1= (int*)(base + 103200000);                    // 6.4 MB
  int* deg2 = (int*)(base + 109600000);                    // 80 KB
  int* R2   = (int*)(base + 109680000);                    // 80 KB
  int* esrc2= (int*)(base + 109760000);                    // 1.28 MB
  int* H1   = (int*)(base + 111040000);                    // 200,704 B
  int* H2   = (int*)(base + 111240704);                    // 10,240 B
  char* misc = base + 111250944;
  int* T1  = (int*)(misc);
  int* Bb1 = (int*)(misc + 1024);
  int* T2  = (int*)(misc + 2048);
  int* Bb2 = (int*)(misc + 3072);
  int* part1 = (int*)(misc + 4096);
  int* part2 = (int*)(misc + 5120);
  uint16_t* wfragG  = (uint16_t*)(misc + 6144);            // 128 KB (frag order)
  uint16_t* w2fragG = wfragG + 65536;                      // 64 KB (frag order)

  if (ws_size < 112000000u) return;

  // ---- fused converts + csr_count ----
  cvt_count<<<25368, 256, 0, stream>>>(x, W_l1, W_r1, W_l2, W_r2, dst1, dst2,
                                       x_bf, wfragG, w2fragG, H1, H2);

  // ---- dual-layer CSR build ----
  csr_scan<<<NBK1 + NBK2, 256, 0, stream>>>(H1, H2, T1, T2);
  csr_base<<<2, 256, 0, stream>>>(T1, T2, Bb1, Bb2);
  csr_place<<<G1 + G2, 256, 0, stream>>>(src1, dst1, src2, dst2, H1, H2,
                                         Bb1, Bb2, pairs1, pairs2);
  csr_bdeg_scan<<<NBK1 + NBK2, 256, 0, stream>>>(pairs1, pairs2, Bb1, Bb2,
                                                 T1, T2, deg1, deg2, R1, R2,
                                                 part1, part2);
  csr_scan_part<<<2, 256, 0, stream>>>(part1, part2);
  csr_bplace<<<NBK1 + NBK2, 256, 0, stream>>>(pairs1, pairs2, Bb1, Bb2, T1, T2,
                                              R1, R2, part1, part2, esrc1, esrc2);

  // ---- gather1 -> mega -> fused gather2+finalize ----
  sage_gather1<<<(CN1 + 3) / 4, 256, 0, stream>>>(x_bf, esrc1, R1, part1, deg1, agg_bf);
  sage_mega<<<(CN1 + 127) / 128, 256, 0, stream>>>(
      agg_bf, x_bf, wfragG, w2fragG, b_l1, t2_bf, out);
  sage_gather2_fin<<<(CN2 + 7) / 8, 256, 0, stream>>>(
      t2_bf, esrc2, R2, part2, deg2, b_l2, out);
}

// Round 16
// 180.412 us; speedup vs baseline: 1.0896x; 1.0896x over previous
//
#include <hip/hip_runtime.h>
#include <hip/hip_fp8.h>
#include <stdint.h>

// SAGE_876173328847: 2-layer bipartite SAGEConv (mean agg) + log_softmax.
// N0=200000, N1=100000, N2=20000, E1=1.6M, E2=320K, D_IN=128, D_H=256, D_OUT=64.
//
// R1: atomic scatter -> CSR build + gather (3309 -> 667 us).
// R2/R3: bf16 heavy path + MFMA GEMMs (667 -> 547 us).
// R4: fused mega-kernel, h1 lives only in LDS (547 -> 472 us).
// R7: scan-based multi-split CSR build, zero global atomics (-> 366 us).
// R8: spill-free mega (-> 347). R9: launch fusion (-> 285).
// R11: 32x32x16 MFMA fused mega (-> 264). R12: fragment-order W (-> 212).
// R13/R14/R15: gather tuning converged at 62-64 us — line-service-bound on
//      random 256B rows (FETCH pinned at 194 MB across 3 implementations).
// R16: fp8 gather path: x stored ALSO as OCP e4m3 (rows 128B = 2 lines,
//      halves gather line count). Decode via hw cvt_pk_f32_fp8; f32 accum;
//      agg still bf16; mega's direct x-path stays bf16. Workspace unchanged
//      (~111.5 MB) via lifetime aliasing: x_fp8 <-> t2, pairs <-> agg.

#define CN0 200000
#define CN1 100000
#define CN2 20000
#define CE1 1600000
#define CE2 320000
#define CD_IN 128
#define CD_H 256
#define CD_OUT 64

// multi-split geometry: bucket = dst >> 9 (512 dsts per bucket)
#define NBK1 196          // ceil(N1/512)
#define NBK2 40           // ceil(N2/512)
#define G1 256
#define G2 64
#define CHUNK1 6250       // E1 / G1
#define CHUNK2 5000       // E2 / G2

typedef __bf16 bf16x8 __attribute__((ext_vector_type(8)));
typedef float f32x2 __attribute__((ext_vector_type(2)));
typedef float f32x4 __attribute__((ext_vector_type(4)));
typedef float f32x16 __attribute__((ext_vector_type(16)));
typedef uint16_t u16x4 __attribute__((ext_vector_type(4)));

__device__ inline uint16_t f2bf(float f) {
  uint32_t u = __float_as_uint(f);
  return (uint16_t)((u + 0x7fffu + ((u >> 16) & 1u)) >> 16);
}
__device__ inline float blo(uint32_t v) { return __uint_as_float(v << 16); }
__device__ inline float bhi(uint32_t v) { return __uint_as_float(v & 0xffff0000u); }

// ---- fp8 (OCP e4m3) helpers ----
__device__ inline uint32_t f32x4_to_fp8x4(float a, float b, float c, float d) {
#if __has_builtin(__builtin_amdgcn_cvt_pk_fp8_f32)
  uint32_t pk = (uint32_t)__builtin_amdgcn_cvt_pk_fp8_f32(a, b, 0, false);
  pk = (uint32_t)__builtin_amdgcn_cvt_pk_fp8_f32(c, d, (int)pk, true);
  return pk;
#else
  __hip_fp8_e4m3 e0(a), e1(b), e2(c), e3(d);
  return (uint32_t)e0.__x | ((uint32_t)e1.__x << 8) |
         ((uint32_t)e2.__x << 16) | ((uint32_t)e3.__x << 24);
#endif
}

__device__ inline float fp8_one(uint32_t b) {   // fallback scalar decode
  uint32_t s = (b >> 7) & 1u, e = (b >> 3) & 15u, m = b & 7u;
  float f = (e == 0) ? (float)m * 0.001953125f
                     : __uint_as_float(((e + 120u) << 23) | (m << 20));
  return s ? -f : f;
}

__device__ inline void fp8x4_acc(uint32_t w, float& p0, float& p1,
                                 float& p2, float& p3) {
#if __has_builtin(__builtin_amdgcn_cvt_pk_f32_fp8)
  f32x2 lo = __builtin_amdgcn_cvt_pk_f32_fp8(w, false);
  f32x2 hi = __builtin_amdgcn_cvt_pk_f32_fp8(w, true);
  p0 += lo[0]; p1 += lo[1]; p2 += hi[0]; p3 += hi[1];
#else
  p0 += fp8_one(w & 0xffu);
  p1 += fp8_one((w >> 8) & 0xffu);
  p2 += fp8_one((w >> 16) & 0xffu);
  p3 += fp8_one((w >> 24) & 0xffu);
#endif
}

// ---- fused: x convert bf16+fp8 (25000 blk) + weight frags (48) + csr_count (320) ----
__global__ __launch_bounds__(256) void cvt_count(
    const float* __restrict__ x, const float* __restrict__ Wl1,
    const float* __restrict__ Wr1, const float* __restrict__ Wl2,
    const float* __restrict__ Wr2, const int* __restrict__ dst1,
    const int* __restrict__ dst2, uint16_t* __restrict__ x_bf,
    uint32_t* __restrict__ x_fp8, uint16_t* __restrict__ wfragG,
    uint16_t* __restrict__ w2fragG, int* __restrict__ H1, int* __restrict__ H2) {
  __shared__ int hist[256];
  int blk = blockIdx.x;
  if (blk < 25000) {
    int i = blk * 256 + threadIdx.x;      // < 6,400,000 float4s
    float4 v = reinterpret_cast<const float4*>(x)[i];
    u16x4 o = {f2bf(v.x), f2bf(v.y), f2bf(v.z), f2bf(v.w)};
    reinterpret_cast<u16x4*>(x_bf)[i] = o;
    x_fp8[i] = f32x4_to_fp8x4(v.x, v.y, v.z, v.w);
    return;
  }
  if (blk < 25048) {
    int c = (blk - 25000) * 256 + threadIdx.x;   // 0..12287
    uint16_t o[8];
    if (c < 8192) {
      int lane = c & 63, t = (c >> 6) & 15, n = c >> 10;
      int row = n * 32 + (lane & 31);
      int kk = t * 16 + (lane >> 5) * 8;
      const float* srcp = (kk < 128) ? (Wl1 + (size_t)row * 128 + kk)
                                     : (Wr1 + (size_t)row * 128 + (kk - 128));
#pragma unroll
      for (int e = 0; e < 8; ++e) o[e] = f2bf(srcp[e]);
      *reinterpret_cast<int4*>(wfragG + (size_t)c * 8) = *reinterpret_cast<int4*>(o);
    } else {
      int cc = c - 8192;                    // 0..4095
      int lane = cc & 63, tt = (cc >> 6) & 15, j = cc >> 10;
      int row = j * 32 + (lane & 31);
      int kk = tt * 16 + (lane >> 5) * 8;
      const float* srcp = (row < 64) ? (Wl2 + (size_t)row * 256 + kk)
                                     : (Wr2 + (size_t)(row - 64) * 256 + kk);
#pragma unroll
      for (int e = 0; e < 8; ++e) o[e] = f2bf(srcp[e]);
      *reinterpret_cast<int4*>(w2fragG + (size_t)cc * 8) = *reinterpret_cast<int4*>(o);
    }
    return;
  }
  // ---- histogram chunk ----
  int g = blk - 25048, t = threadIdx.x;
  const int* dst; int* H; int E, nb, chunk;
  if (g < G1) { dst = dst1; H = H1; E = CE1; nb = NBK1; chunk = CHUNK1; }
  else { g -= G1; dst = dst2; H = H2; E = CE2; nb = NBK2; chunk = CHUNK2; }
  hist[t] = 0;
  __syncthreads();
  int e0 = g * chunk, e1 = min(e0 + chunk, E);
  for (int e = e0 + t; e < e1; e += 256) atomicAdd(&hist[dst[e] >> 9], 1);
  __syncthreads();
  if (t < nb) H[g * nb + t] = hist[t];
}

// ---------------- dual-layer scan-based multi-split ----------------
__global__ __launch_bounds__(256) void csr_scan(
    int* __restrict__ H1, int* __restrict__ H2,
    int* __restrict__ T1, int* __restrict__ T2) {
  __shared__ int sm[256];
  int b = blockIdx.x, t = threadIdx.x;
  int* H; int* T; int nb, G;
  if (b < NBK1) { H = H1; T = T1; nb = NBK1; G = G1; }
  else { b -= NBK1; H = H2; T = T2; nb = NBK2; G = G2; }
  int v = (t < G) ? H[t * nb + b] : 0;
  sm[t] = v;
  __syncthreads();
#pragma unroll
  for (int off = 1; off < 256; off <<= 1) {
    int u = (t >= off) ? sm[t - off] : 0;
    __syncthreads();
    sm[t] += u;
    __syncthreads();
  }
  if (t < G) H[t * nb + b] = sm[t] - v;  // exclusive over chunks
  if (t == 255) T[b] = sm[255];          // bucket total
}

__global__ __launch_bounds__(256) void csr_base(
    const int* __restrict__ T1, const int* __restrict__ T2,
    int* __restrict__ Bb1, int* __restrict__ Bb2) {
  __shared__ int sm[256];
  int t = threadIdx.x;
  const int* T; int* Bb; int nb;
  if (blockIdx.x == 0) { T = T1; Bb = Bb1; nb = NBK1; }
  else { T = T2; Bb = Bb2; nb = NBK2; }
  int v = (t < nb) ? T[t] : 0;
  sm[t] = v;
  __syncthreads();
#pragma unroll
  for (int off = 1; off < 256; off <<= 1) {
    int u = (t >= off) ? sm[t - off] : 0;
    __syncthreads();
    sm[t] += u;
    __syncthreads();
  }
  if (t < nb) Bb[t] = sm[t] - v;
}

__global__ __launch_bounds__(256) void csr_place(
    const int* __restrict__ src1, const int* __restrict__ dst1,
    const int* __restrict__ src2, const int* __restrict__ dst2,
    const int* __restrict__ H1, const int* __restrict__ H2,
    const int* __restrict__ Bb1, const int* __restrict__ Bb2,
    uint32_t* __restrict__ pairs1, uint32_t* __restrict__ pairs2) {
  __shared__ int curs[256];
  int g = blockIdx.x, t = threadIdx.x;
  const int* src; const int* dst; const int* H; const int* Bb;
  uint32_t* pairs; int E, nb, chunk;
  if (g < G1) { src = src1; dst = dst1; H = H1; Bb = Bb1; pairs = pairs1;
                E = CE1; nb = NBK1; chunk = CHUNK1; }
  else { g -= G1; src = src2; dst = dst2; H = H2; Bb = Bb2; pairs = pairs2;
         E = CE2; nb = NBK2; chunk = CHUNK2; }
  if (t < nb) curs[t] = Bb[t] + H[g * nb + t];
  __syncthreads();
  int e0 = g * chunk, e1 = min(e0 + chunk, E);
  for (int e = e0 + t; e < e1; e += 256) {
    int d = dst[e];
    int b = d >> 9;
    int p = atomicAdd(&curs[b], 1);
    pairs[p] = (uint32_t)src[e] | ((uint32_t)(d & 511) << 18);
  }
}

// ---- FUSED bdeg + scan_local ----
__global__ __launch_bounds__(256) void csr_bdeg_scan(
    const uint32_t* __restrict__ pairs1, const uint32_t* __restrict__ pairs2,
    const int* __restrict__ Bb1, const int* __restrict__ Bb2,
    const int* __restrict__ T1, const int* __restrict__ T2,
    int* __restrict__ deg1, int* __restrict__ deg2,
    int* __restrict__ R1, int* __restrict__ R2,
    int* __restrict__ part1, int* __restrict__ part2) {
  __shared__ int cnt[512];
  __shared__ int sm[256];
  int b = blockIdx.x, t = threadIdx.x;
  const uint32_t* pairs; const int* Bb; const int* T;
  int* deg; int* R; int* part; int ndst;
  if (b < NBK1) { pairs = pairs1; Bb = Bb1; T = T1; deg = deg1; R = R1;
                  part = part1; ndst = CN1; }
  else { b -= NBK1; pairs = pairs2; Bb = Bb2; T = T2; deg = deg2; R = R2;
         part = part2; ndst = CN2; }
  cnt[t] = 0;
  cnt[t + 256] = 0;
  __syncthreads();
  int s0 = Bb[b], n = T[b];
  for (int i = t; i < n; i += 256) atomicAdd(&cnt[pairs[s0 + i] >> 18], 1);
  __syncthreads();
  int d0 = b << 9;
  int a = cnt[2 * t], c = cnt[2 * t + 1];
  int i0 = d0 + 2 * t, i1 = d0 + 2 * t + 1;
  if (i0 < ndst) deg[i0] = a;
  if (i1 < ndst) deg[i1] = c;
  int s = a + c;
  sm[t] = s;
  __syncthreads();
#pragma unroll
  for (int off = 1; off < 256; off <<= 1) {
    int u = (t >= off) ? sm[t - off] : 0;
    __syncthreads();
    sm[t] += u;
    __syncthreads();
  }
  int excl = sm[t] - s;
  if (i0 < ndst) R[i0] = excl;
  if (i1 < ndst) R[i1] = excl + a;
  if (t == 255) part[b] = sm[255];
}

__global__ __launch_bounds__(256) void csr_scan_part(
    int* __restrict__ part1, int* __restrict__ part2) {
  __shared__ int sm[256];
  int t = threadIdx.x;
  int* part; int B;
  if (blockIdx.x == 0) { part = part1; B = NBK1; }
  else { part = part2; B = NBK2; }
  int v = (t < B) ? part[t] : 0;
  sm[t] = v;
  __syncthreads();
#pragma unroll
  for (int off = 1; off < 256; off <<= 1) {
    int u = (t >= off) ? sm[t - off] : 0;
    __syncthreads();
    sm[t] += u;
    __syncthreads();
  }
  if (t < B) part[t] = sm[t] - v;
}

// bplace with addback folded in: final offset = R[dd] + part[bucket]
__global__ __launch_bounds__(256) void csr_bplace(
    const uint32_t* __restrict__ pairs1, const uint32_t* __restrict__ pairs2,
    const int* __restrict__ Bb1, const int* __restrict__ Bb2,
    const int* __restrict__ T1, const int* __restrict__ T2,
    const int* __restrict__ R1, const int* __restrict__ R2,
    const int* __restrict__ part1, const int* __restrict__ part2,
    int* __restrict__ esrc1, int* __restrict__ esrc2) {
  __shared__ int curs[512];
  int b = blockIdx.x, t = threadIdx.x;
  const uint32_t* pairs; const int* Bb; const int* T; const int* R;
  const int* part; int* esrc; int ndst;
  if (b < NBK1) { pairs = pairs1; Bb = Bb1; T = T1; R = R1; part = part1;
                  esrc = esrc1; ndst = CN1; }
  else { b -= NBK1; pairs = pairs2; Bb = Bb2; T = T2; R = R2; part = part2;
         esrc = esrc2; ndst = CN2; }
  int d0 = b << 9;
  int pb = part[b];
#pragma unroll
  for (int j = 0; j < 2; ++j) {
    int dd = d0 + t + j * 256;
    curs[t + j * 256] = (dd < ndst) ? R[dd] + pb : 0;
  }
  __syncthreads();
  int s0 = Bb[b], n = T[b];
  for (int i = t; i < n; i += 256) {
    uint32_t pk = pairs[s0 + i];
    int p = atomicAdd(&curs[pk >> 18], 1);
    esrc[p] = (int)(pk & 0x3FFFFu);
  }
}

// ------- gather-mean layer 1 (R16): fp8 rows (128B), one dst per WAVE,
// 16 lanes/row x uint2 (8 fp8), 4 edge-subgroups, 16-edge main loop -------
__global__ __launch_bounds__(256) void sage_gather1(
    const uint32_t* __restrict__ xf8, const int* __restrict__ esrc,
    const int* __restrict__ R, const int* __restrict__ part,
    const int* __restrict__ deg, uint16_t* __restrict__ agg) {
  const int d = __builtin_amdgcn_readfirstlane(blockIdx.x * 4 + (threadIdx.x >> 6));
  const int lane = threadIdx.x & 63;
  const int cc = lane & 15;    // 8-byte chunk within row (cols 8cc..8cc+7)
  const int h = lane >> 4;     // 0..3 edge subgroup
  const int start = __builtin_amdgcn_readfirstlane(R[d] + part[d >> 9]);
  const int n = __builtin_amdgcn_readfirstlane(deg[d]);
  const uint2* xw = reinterpret_cast<const uint2*>(xf8);   // row = 16 uint2
  float a0 = 0.f, a1 = 0.f, a2 = 0.f, a3 = 0.f;
  float a4 = 0.f, a5 = 0.f, a6 = 0.f, a7 = 0.f;
  float c0 = 0.f, c1 = 0.f, c2 = 0.f, c3 = 0.f;
  float c4 = 0.f, c5 = 0.f, c6 = 0.f, c7 = 0.f;
  int i = 0;
  for (; i + 16 <= n; i += 16) {
    int s0 = esrc[start + i + h];
    int s1 = esrc[start + i + 4 + h];
    int s2 = esrc[start + i + 8 + h];
    int s3 = esrc[start + i + 12 + h];
    uint2 v0 = xw[(uint32_t)s0 * 16u + cc];
    uint2 v1 = xw[(uint32_t)s1 * 16u + cc];
    uint2 v2 = xw[(uint32_t)s2 * 16u + cc];
    uint2 v3 = xw[(uint32_t)s3 * 16u + cc];
    fp8x4_acc(v0.x, a0, a1, a2, a3);
    fp8x4_acc(v0.y, a4, a5, a6, a7);
    fp8x4_acc(v1.x, a0, a1, a2, a3);
    fp8x4_acc(v1.y, a4, a5, a6, a7);
    fp8x4_acc(v2.x, c0, c1, c2, c3);
    fp8x4_acc(v2.y, c4, c5, c6, c7);
    fp8x4_acc(v3.x, c0, c1, c2, c3);
    fp8x4_acc(v3.y, c4, c5, c6, c7);
  }
  for (; i + 4 <= n; i += 4) {
    int s0 = esrc[start + i + h];
    uint2 v = xw[(uint32_t)s0 * 16u + cc];
    fp8x4_acc(v.x, a0, a1, a2, a3);
    fp8x4_acc(v.y, a4, a5, a6, a7);
  }
  if (i < n && h < n - i) {
    int s0 = esrc[start + i + h];
    uint2 v = xw[(uint32_t)s0 * 16u + cc];
    fp8x4_acc(v.x, a0, a1, a2, a3);
    fp8x4_acc(v.y, a4, a5, a6, a7);
  }
  a0 += c0; a1 += c1; a2 += c2; a3 += c3;
  a4 += c4; a5 += c5; a6 += c6; a7 += c7;
  // reduce across the 4 subgroups (lanes 16 and 32 apart)
  a0 += __shfl_xor(a0, 16); a0 += __shfl_xor(a0, 32);
  a1 += __shfl_xor(a1, 16); a1 += __shfl_xor(a1, 32);
  a2 += __shfl_xor(a2, 16); a2 += __shfl_xor(a2, 32);
  a3 += __shfl_xor(a3, 16); a3 += __shfl_xor(a3, 32);
  a4 += __shfl_xor(a4, 16); a4 += __shfl_xor(a4, 32);
  a5 += __shfl_xor(a5, 16); a5 += __shfl_xor(a5, 32);
  a6 += __shfl_xor(a6, 16); a6 += __shfl_xor(a6, 32);
  a7 += __shfl_xor(a7, 16); a7 += __shfl_xor(a7, 32);
  if (lane < 16) {
    float inv = 1.0f / fmaxf((float)n, 1.0f);
    uint4 o;
    o.x = (uint32_t)f2bf(a0 * inv) | ((uint32_t)f2bf(a1 * inv) << 16);
    o.y = (uint32_t)f2bf(a2 * inv) | ((uint32_t)f2bf(a3 * inv) << 16);
    o.z = (uint32_t)f2bf(a4 * inv) | ((uint32_t)f2bf(a5 * inv) << 16);
    o.w = (uint32_t)f2bf(a6 * inv) | ((uint32_t)f2bf(a7 * inv) << 16);
    reinterpret_cast<uint4*>(agg)[(size_t)d * 16 + cc] = o;
  }
}

// ------- FUSED gather-mean layer 2 + log_softmax finalize -------
__global__ __launch_bounds__(256) void sage_gather2_fin(
    const uint16_t* __restrict__ t2, const int* __restrict__ esrc,
    const int* __restrict__ R, const int* __restrict__ part,
    const int* __restrict__ deg, const float* __restrict__ b2,
    float* __restrict__ out) {
  int d = blockIdx.x * 8 + (threadIdx.x >> 5);
  int c = threadIdx.x & 31;
  if (d >= CN2) return;
  int start = R[d] + part[d >> 9], n = deg[d];
  const uint32_t* tw = reinterpret_cast<const uint32_t*>(t2);
  float a0 = 0.f, a1 = 0.f, b0 = 0.f, b1 = 0.f;
  int i = 0;
  for (; i + 8 <= n; i += 8) {
    int s0 = esrc[start + i + 0], s1 = esrc[start + i + 1];
    int s2 = esrc[start + i + 2], s3 = esrc[start + i + 3];
    int s4 = esrc[start + i + 4], s5 = esrc[start + i + 5];
    int s6 = esrc[start + i + 6], s7 = esrc[start + i + 7];
    uint32_t v0 = tw[(size_t)s0 * 32 + c], v1 = tw[(size_t)s1 * 32 + c];
    uint32_t v2 = tw[(size_t)s2 * 32 + c], v3 = tw[(size_t)s3 * 32 + c];
    uint32_t v4 = tw[(size_t)s4 * 32 + c], v5 = tw[(size_t)s5 * 32 + c];
    uint32_t v6 = tw[(size_t)s6 * 32 + c], v7 = tw[(size_t)s7 * 32 + c];
    a0 += (blo(v0) + blo(v1)) + (blo(v2) + blo(v3));
    b0 += (blo(v4) + blo(v5)) + (blo(v6) + blo(v7));
    a1 += (bhi(v0) + bhi(v1)) + (bhi(v2) + bhi(v3));
    b1 += (bhi(v4) + bhi(v5)) + (bhi(v6) + bhi(v7));
  }
  for (; i + 2 <= n; i += 2) {
    int s0 = esrc[start + i + 0], s1 = esrc[start + i + 1];
    uint32_t v0 = tw[(size_t)s0 * 32 + c], v1 = tw[(size_t)s1 * 32 + c];
    a0 += blo(v0) + blo(v1);
    a1 += bhi(v0) + bhi(v1);
  }
  if (i < n) {
    uint32_t v = tw[(size_t)esrc[start + i] * 32 + c];
    a0 += blo(v);
    a1 += bhi(v);
  }
  a0 += b0; a1 += b1;
  float inv = 1.0f / fmaxf((float)n, 1.0f);

  float2 ov = reinterpret_cast<const float2*>(out)[(size_t)d * 32 + c];
  float2 bb = reinterpret_cast<const float2*>(b2)[c];
  float v0 = ov.x + a0 * inv + bb.x;
  float v1 = ov.y + a1 * inv + bb.y;
  float m = fmaxf(v0, v1);
#pragma unroll
  for (int off = 16; off > 0; off >>= 1) m = fmaxf(m, __shfl_xor(m, off));
  float s = expf(v0 - m) + expf(v1 - m);
#pragma unroll
  for (int off = 16; off > 0; off >>= 1) s += __shfl_xor(s, off);
  float lg = logf(s);
  float2 r;
  r.x = v0 - m - lg;
  r.y = v1 - m - lg;
  reinterpret_cast<float2*>(out)[(size_t)d * 32 + c] = r;
}

// ---------------- MEGA kernel (R12: LDS-staged fragment-order W) ----------------
__global__ __launch_bounds__(256, 2) void sage_mega(
    const uint16_t* __restrict__ agg, const uint16_t* __restrict__ xbf,
    const uint16_t* __restrict__ wfragG, const uint16_t* __restrict__ w2fragG,
    const float* __restrict__ bias, uint16_t* __restrict__ t2,
    float* __restrict__ outp) {
  __shared__ uint16_t wfrag[32768];       // 64 KB: 64 chunks x 512 shorts
  __shared__ uint16_t h1t[4 * 32 * 40];   // 10240 B; per-wave 32x40 transpose tile
  const int tid = threadIdx.x;
  const int w = tid >> 6;
  const int lane = tid & 63;
  const int lcol = lane & 31;             // A-row / B-col / C-col
  const int hi = lane >> 5;               // k-half (frags) / row +4 (C)
  const int row0 = blockIdx.x * 128 + w * 32;
  uint16_t* hw = &h1t[w * (32 * 40)];

  // A fragments: 16 k-tiles of K=16 from [agg | x]; lane: row=lcol, k=hi*8..+7
  int arow = row0 + lcol;
  arow = arow < CN1 ? arow : CN1 - 1;
  bf16x8 afr[16];
#pragma unroll
  for (int t = 0; t < 16; ++t) {
    const uint16_t* Asrc = (t < 8) ? agg : xbf;
    const int koff = (t < 8) ? t * 16 : t * 16 - 128;
    afr[t] = *reinterpret_cast<const bf16x8*>(
        Asrc + (size_t)arow * CD_IN + koff + hi * 8);
  }

  const bool do_out = (row0 < CN2);       // CN2 % 32 == 0 -> wave-uniform
  bf16x8 a2[16];                          // h1 A-frags, filled per n (static idx)

#pragma unroll
  for (int h = 0; h < 2; ++h) {
    // stage half h of W1 fragments: 64 chunks x 1 KB, 16 per wave, coalesced
#pragma unroll
    for (int i = 0; i < 16; ++i) {
      int cc = i * 4 + w;
      int4 v = *reinterpret_cast<const int4*>(
          wfragG + (size_t)(h * 64 + cc) * 512 + lane * 8);
      *reinterpret_cast<int4*>(&wfrag[cc * 512 + lane * 8]) = v;
    }
    __syncthreads();
#pragma unroll
    for (int nn = 0; nn < 4; ++nn) {
      const int n = h * 4 + nn;
      const float bb = bias[n * 32 + lcol];
      f32x16 p0 = (f32x16)0.0f, p1 = (f32x16)0.0f;
#pragma unroll
      for (int t = 0; t < 16; t += 2) {
        bf16x8 b0 = *reinterpret_cast<const bf16x8*>(
            &wfrag[((nn * 16 + t) * 64 + lane) * 8]);
        bf16x8 b1 = *reinterpret_cast<const bf16x8*>(
            &wfrag[((nn * 16 + t + 1) * 64 + lane) * 8]);
        p0 = __builtin_amdgcn_mfma_f32_32x32x16_bf16(afr[t], b0, p0, 0, 0, 0);
        p1 = __builtin_amdgcn_mfma_f32_32x32x16_bf16(afr[t + 1], b1, p1, 0, 0, 0);
      }
      // bias + relu -> bf16 -> per-wave LDS transpose tile (C layout m74/m101)
#pragma unroll
      for (int r = 0; r < 16; ++r) {
        float v = fmaxf(p0[r] + p1[r] + bb, 0.0f);
        int R = (r & 3) + 8 * (r >> 2) + 4 * hi;
        hw[R * 40 + lcol] = f2bf(v);
      }
      // read back as phase-2 A-frags (k = n*32 + {0..15, 16..31})
      a2[n * 2 + 0] = *reinterpret_cast<const bf16x8*>(&hw[lcol * 40 + hi * 8]);
      a2[n * 2 + 1] = *reinterpret_cast<const bf16x8*>(&hw[lcol * 40 + 16 + hi * 8]);
    }
    __syncthreads();   // all waves done reading this half before overwrite
  }

  // stage w2 fragments (64 KB) into the same buffer
#pragma unroll
  for (int i = 0; i < 16; ++i) {
    int cc = i * 4 + w;
    int4 v = *reinterpret_cast<const int4*>(
        w2fragG + (size_t)cc * 512 + lane * 8);
    *reinterpret_cast<int4*>(&wfrag[cc * 512 + lane * 8]) = v;
  }
  __syncthreads();

  // ---- phase 2: jp=0 -> t2 cols (j=0,1); jp=1 -> out cols (j=2,3) ----
#pragma unroll
  for (int jp = 0; jp < 2; ++jp) {
    if (jp == 1 && !do_out) break;
    const int jA = jp * 2, jB = jp * 2 + 1;
    f32x16 aA = (f32x16)0.0f, aB = (f32x16)0.0f;
#pragma unroll
    for (int s = 0; s < 8; ++s) {
      bf16x8 c0A = *reinterpret_cast<const bf16x8*>(
          &wfrag[((jA * 16 + s * 2) * 64 + lane) * 8]);
      bf16x8 c1A = *reinterpret_cast<const bf16x8*>(
          &wfrag[((jA * 16 + s * 2 + 1) * 64 + lane) * 8]);
      bf16x8 c0B = *reinterpret_cast<const bf16x8*>(
          &wfrag[((jB * 16 + s * 2) * 64 + lane) * 8]);
      bf16x8 c1B = *reinterpret_cast<const bf16x8*>(
          &wfrag[((jB * 16 + s * 2 + 1) * 64 + lane) * 8]);
      aA = __builtin_amdgcn_mfma_f32_32x32x16_bf16(a2[s * 2], c0A, aA, 0, 0, 0);
      aB = __builtin_amdgcn_mfma_f32_32x32x16_bf16(a2[s * 2], c0B, aB, 0, 0, 0);
      aA = __builtin_amdgcn_mfma_f32_32x32x16_bf16(a2[s * 2 + 1], c1A, aA, 0, 0, 0);
      aB = __builtin_amdgcn_mfma_f32_32x32x16_bf16(a2[s * 2 + 1], c1B, aB, 0, 0, 0);
    }
    if (jp == 0) {
#pragma unroll
      for (int r = 0; r < 16; ++r) {
        int R = (r & 3) + 8 * (r >> 2) + 4 * hi;
        int rg = row0 + R;
        if (rg < CN1) {
          t2[(size_t)rg * 64 + lcol] = f2bf(aA[r]);
          t2[(size_t)rg * 64 + 32 + lcol] = f2bf(aB[r]);
        }
      }
    } else {
#pragma unroll
      for (int r = 0; r < 16; ++r) {
        int R = (r & 3) + 8 * (r >> 2) + 4 * hi;
        int rg = row0 + R;
        outp[(size_t)rg * 64 + lcol] = aA[r];
        outp[(size_t)rg * 64 + 32 + lcol] = aB[r];
      }
    }
  }
}

extern "C" void kernel_launch(void* const* d_in, const int* in_sizes, int n_in,
                              void* d_out, int out_size, void* d_ws, size_t ws_size,
                              hipStream_t stream) {
  const float* x    = (const float*)d_in[0];
  const int* src1   = (const int*)d_in[1];
  const int* dst1   = (const int*)d_in[2];
  const int* src2   = (const int*)d_in[3];
  const int* dst2   = (const int*)d_in[4];
  const float* W_l1 = (const float*)d_in[5];
  const float* b_l1 = (const float*)d_in[6];
  const float* W_r1 = (const float*)d_in[7];
  const float* W_l2 = (const float*)d_in[8];
  const float* b_l2 = (const float*)d_in[9];
  const float* W_r2 = (const float*)d_in[10];
  float* out = (float*)d_out;
  char* base = (char*)d_ws;

  // ---- workspace layout (bytes), ~111.5 MB, lifetime-aliased ----
  // [0, 51.2M)        x_bf  [N0][128] bf16            (cvt -> mega)
  // [51.2M, 76.8M)    x_fp8 [N0][128] e4m3            (cvt -> gather1)
  //                     t2_bf [N1][64] bf16 aliases [51.2M, 64M) (mega -> g2fin)
  // [76.8M, 102.4M)   agg_bf [N1][128] bf16           (gather1 -> mega)
  //                     pairs1 aliases [76.8M, 83.2M); pairs2 [83.2M, 84.48M)
  //                     (place -> bplace, dead before gather1 writes agg)
  // [102.4M, ...]     CSR ints + weight frags
  uint16_t* x_bf  = (uint16_t*)base;
  uint32_t* x_fp8 = (uint32_t*)(base + 51200000);
  uint16_t* t2_bf = (uint16_t*)(base + 51200000);          // alias (after gather1)
  uint16_t* agg_bf= (uint16_t*)(base + 76800000);
  uint32_t* pairs1= (uint32_t*)(base + 76800000);          // alias (before gather1)
  uint32_t* pairs2= (uint32_t*)(base + 83200000);          // alias
  int* deg1 = (int*)(base + 102400000);                    // 400 KB
  int* R1   = (int*)(base + 102800000);                    // 400 KB
  int* esrc1= (int*)(base + 103200000);                    // 6.4 MB
  int* deg2 = (int*)(base + 109600000);                    // 80 KB
  int* R2   = (int*)(base + 109680000);                    // 80 KB
  int* esrc2= (int*)(base + 109760000);                    // 1.28 MB
  int* H1   = (int*)(base + 111040000);                    // 200,704 B
  int* H2   = (int*)(base + 111240704);                    // 10,240 B
  char* misc = base + 111250944;
  int* T1  = (int*)(misc);
  int* Bb1 = (int*)(misc + 1024);
  int* T2  = (int*)(misc + 2048);
  int* Bb2 = (int*)(misc + 3072);
  int* part1 = (int*)(misc + 4096);
  int* part2 = (int*)(misc + 5120);
  uint16_t* wfragG  = (uint16_t*)(misc + 6144);            // 128 KB (frag order)
  uint16_t* w2fragG = wfragG + 65536;                      // 64 KB (frag order)

  if (ws_size < 112000000u) return;

  // ---- fused converts (bf16 + fp8) + csr_count ----
  cvt_count<<<25368, 256, 0, stream>>>(x, W_l1, W_r1, W_l2, W_r2, dst1, dst2,
                                       x_bf, x_fp8, wfragG, w2fragG, H1, H2);

  // ---- dual-layer CSR build ----
  csr_scan<<<NBK1 + NBK2, 256, 0, stream>>>(H1, H2, T1, T2);
  csr_base<<<2, 256, 0, stream>>>(T1, T2, Bb1, Bb2);
  csr_place<<<G1 + G2, 256, 0, stream>>>(src1, dst1, src2, dst2, H1, H2,
                                         Bb1, Bb2, pairs1, pairs2);
  csr_bdeg_scan<<<NBK1 + NBK2, 256, 0, stream>>>(pairs1, pairs2, Bb1, Bb2,
                                                 T1, T2, deg1, deg2, R1, R2,
                                                 part1, part2);
  csr_scan_part<<<2, 256, 0, stream>>>(part1, part2);
  csr_bplace<<<NBK1 + NBK2, 256, 0, stream>>>(pairs1, pairs2, Bb1, Bb2, T1, T2,
                                              R1, R2, part1, part2, esrc1, esrc2);

  // ---- gather1 (fp8) -> mega -> fused gather2+finalize ----
  sage_gather1<<<(CN1 + 3) / 4, 256, 0, stream>>>(x_fp8, esrc1, R1, part1, deg1, agg_bf);
  sage_mega<<<(CN1 + 127) / 128, 256, 0, stream>>>(
      agg_bf, x_bf, wfragG, w2fragG, b_l1, t2_bf, out);
  sage_gather2_fin<<<(CN2 + 7) / 8, 256, 0, stream>>>(
      t2_bf, esrc2, R2, part2, deg2, b_l2, out);
}

// Round 18
// 173.516 us; speedup vs baseline: 1.1329x; 1.0397x over previous
//
#include <hip/hip_runtime.h>
#include <hip/hip_fp8.h>
#include <stdint.h>

// SAGE_876173328847: 2-layer bipartite SAGEConv (mean agg) + log_softmax.
// N0=200000, N1=100000, N2=20000, E1=1.6M, E2=320K, D_IN=128, D_H=256, D_OUT=64.
//
// R1: atomic scatter -> CSR build + gather (3309 -> 667 us).
// R2/R3: bf16 + MFMA (-> 547). R4: fused mega, h1 in LDS (-> 472).
// R7: scan-based multi-split CSR, zero global atomics (-> 366).
// R8: spill-free mega (-> 347). R9: launch fusion (-> 285).
// R11: 32x32x16 fused mega (-> 264). R12: fragment-order W (-> 212).
// R13-15: gather tuning; converged line-service-bound (-> ~192).
// R16: fp8 e4m3 gather path, rows 128B (-> 180).
// R17: drop x_bf; mega dequantizes direct-path frags from x_fp8. FAILED:
//      fp8 fragment index added koff/8 twice (read wrong columns/rows).
// R18: fix the index: arow*16 + koff/8 + hi.

#define CN0 200000
#define CN1 100000
#define CN2 20000
#define CE1 1600000
#define CE2 320000
#define CD_IN 128
#define CD_H 256
#define CD_OUT 64

// multi-split geometry: bucket = dst >> 9 (512 dsts per bucket)
#define NBK1 196          // ceil(N1/512)
#define NBK2 40           // ceil(N2/512)
#define G1 256
#define G2 64
#define CHUNK1 6250       // E1 / G1
#define CHUNK2 5000       // E2 / G2

typedef __bf16 bf16x8 __attribute__((ext_vector_type(8)));
typedef float f32x2 __attribute__((ext_vector_type(2)));
typedef float f32x4 __attribute__((ext_vector_type(4)));
typedef float f32x16 __attribute__((ext_vector_type(16)));
typedef uint16_t u16x4 __attribute__((ext_vector_type(4)));

__device__ inline uint16_t f2bf(float f) {
  uint32_t u = __float_as_uint(f);
  return (uint16_t)((u + 0x7fffu + ((u >> 16) & 1u)) >> 16);
}
__device__ inline float blo(uint32_t v) { return __uint_as_float(v << 16); }
__device__ inline float bhi(uint32_t v) { return __uint_as_float(v & 0xffff0000u); }

// ---- fp8 (OCP e4m3) helpers ----
__device__ inline uint32_t f32x4_to_fp8x4(float a, float b, float c, float d) {
#if __has_builtin(__builtin_amdgcn_cvt_pk_fp8_f32)
  uint32_t pk = (uint32_t)__builtin_amdgcn_cvt_pk_fp8_f32(a, b, 0, false);
  pk = (uint32_t)__builtin_amdgcn_cvt_pk_fp8_f32(c, d, (int)pk, true);
  return pk;
#else
  __hip_fp8_e4m3 e0(a), e1(b), e2(c), e3(d);
  return (uint32_t)e0.__x | ((uint32_t)e1.__x << 8) |
         ((uint32_t)e2.__x << 16) | ((uint32_t)e3.__x << 24);
#endif
}

__device__ inline float fp8_one(uint32_t b) {   // fallback scalar decode
  uint32_t s = (b >> 7) & 1u, e = (b >> 3) & 15u, m = b & 7u;
  float f = (e == 0) ? (float)m * 0.001953125f
                     : __uint_as_float(((e + 120u) << 23) | (m << 20));
  return s ? -f : f;
}

__device__ inline void fp8x4_dec(uint32_t w, float& p0, float& p1,
                                 float& p2, float& p3) {
#if __has_builtin(__builtin_amdgcn_cvt_pk_f32_fp8)
  f32x2 lo = __builtin_amdgcn_cvt_pk_f32_fp8(w, false);
  f32x2 hi = __builtin_amdgcn_cvt_pk_f32_fp8(w, true);
  p0 = lo[0]; p1 = lo[1]; p2 = hi[0]; p3 = hi[1];
#else
  p0 = fp8_one(w & 0xffu);
  p1 = fp8_one((w >> 8) & 0xffu);
  p2 = fp8_one((w >> 16) & 0xffu);
  p3 = fp8_one((w >> 24) & 0xffu);
#endif
}

__device__ inline void fp8x4_acc(uint32_t w, float& p0, float& p1,
                                 float& p2, float& p3) {
  float q0, q1, q2, q3;
  fp8x4_dec(w, q0, q1, q2, q3);
  p0 += q0; p1 += q1; p2 += q2; p3 += q3;
}

__device__ inline bf16x8 fp8x8_to_bf16x8(uint2 v) {
  float f[8];
  fp8x4_dec(v.x, f[0], f[1], f[2], f[3]);
  fp8x4_dec(v.y, f[4], f[5], f[6], f[7]);
  uint16_t o[8];
#pragma unroll
  for (int e = 0; e < 8; ++e) o[e] = f2bf(f[e]);
  return *reinterpret_cast<bf16x8*>(o);
}

// ---- fused: x->fp8 (12500 blk) + weight frags (48) + csr_count (320) ----
// wfragG : [8 n][16 t][64 lane][8] ; value = Wcat[n*32+(lane&31)][t*16+(lane>>5)*8+e]
// w2fragG: [4 j][16 tt][64 lane][8]; value = W2cat[j*32+(lane&31)][tt*16+(lane>>5)*8+e]
__global__ __launch_bounds__(256) void cvt_count(
    const float* __restrict__ x, const float* __restrict__ Wl1,
    const float* __restrict__ Wr1, const float* __restrict__ Wl2,
    const float* __restrict__ Wr2, const int* __restrict__ dst1,
    const int* __restrict__ dst2, uint32_t* __restrict__ x_fp8,
    uint16_t* __restrict__ wfragG, uint16_t* __restrict__ w2fragG,
    int* __restrict__ H1, int* __restrict__ H2) {
  __shared__ int hist[256];
  int blk = blockIdx.x;
  if (blk < 12500) {
    int i = blk * 256 + threadIdx.x;      // < 3,200,000 (each = 2 float4s)
    const float4* xp = reinterpret_cast<const float4*>(x);
    float4 v0 = xp[2 * i];
    float4 v1 = xp[2 * i + 1];
    uint2 o;
    o.x = f32x4_to_fp8x4(v0.x, v0.y, v0.z, v0.w);
    o.y = f32x4_to_fp8x4(v1.x, v1.y, v1.z, v1.w);
    reinterpret_cast<uint2*>(x_fp8)[i] = o;
    return;
  }
  if (blk < 12548) {
    int c = (blk - 12500) * 256 + threadIdx.x;   // 0..12287
    uint16_t o[8];
    if (c < 8192) {
      int lane = c & 63, t = (c >> 6) & 15, n = c >> 10;
      int row = n * 32 + (lane & 31);
      int kk = t * 16 + (lane >> 5) * 8;
      const float* srcp = (kk < 128) ? (Wl1 + (size_t)row * 128 + kk)
                                     : (Wr1 + (size_t)row * 128 + (kk - 128));
#pragma unroll
      for (int e = 0; e < 8; ++e) o[e] = f2bf(srcp[e]);
      *reinterpret_cast<int4*>(wfragG + (size_t)c * 8) = *reinterpret_cast<int4*>(o);
    } else {
      int cc = c - 8192;                    // 0..4095
      int lane = cc & 63, tt = (cc >> 6) & 15, j = cc >> 10;
      int row = j * 32 + (lane & 31);
      int kk = tt * 16 + (lane >> 5) * 8;
      const float* srcp = (row < 64) ? (Wl2 + (size_t)row * 256 + kk)
                                     : (Wr2 + (size_t)(row - 64) * 256 + kk);
#pragma unroll
      for (int e = 0; e < 8; ++e) o[e] = f2bf(srcp[e]);
      *reinterpret_cast<int4*>(w2fragG + (size_t)cc * 8) = *reinterpret_cast<int4*>(o);
    }
    return;
  }
  // ---- histogram chunk ----
  int g = blk - 12548, t = threadIdx.x;
  const int* dst; int* H; int E, nb, chunk;
  if (g < G1) { dst = dst1; H = H1; E = CE1; nb = NBK1; chunk = CHUNK1; }
  else { g -= G1; dst = dst2; H = H2; E = CE2; nb = NBK2; chunk = CHUNK2; }
  hist[t] = 0;
  __syncthreads();
  int e0 = g * chunk, e1 = min(e0 + chunk, E);
  for (int e = e0 + t; e < e1; e += 256) atomicAdd(&hist[dst[e] >> 9], 1);
  __syncthreads();
  if (t < nb) H[g * nb + t] = hist[t];
}

// ---------------- dual-layer scan-based multi-split ----------------
__global__ __launch_bounds__(256) void csr_scan(
    int* __restrict__ H1, int* __restrict__ H2,
    int* __restrict__ T1, int* __restrict__ T2) {
  __shared__ int sm[256];
  int b = blockIdx.x, t = threadIdx.x;
  int* H; int* T; int nb, G;
  if (b < NBK1) { H = H1; T = T1; nb = NBK1; G = G1; }
  else { b -= NBK1; H = H2; T = T2; nb = NBK2; G = G2; }
  int v = (t < G) ? H[t * nb + b] : 0;
  sm[t] = v;
  __syncthreads();
#pragma unroll
  for (int off = 1; off < 256; off <<= 1) {
    int u = (t >= off) ? sm[t - off] : 0;
    __syncthreads();
    sm[t] += u;
    __syncthreads();
  }
  if (t < G) H[t * nb + b] = sm[t] - v;  // exclusive over chunks
  if (t == 255) T[b] = sm[255];          // bucket total
}

__global__ __launch_bounds__(256) void csr_base(
    const int* __restrict__ T1, const int* __restrict__ T2,
    int* __restrict__ Bb1, int* __restrict__ Bb2) {
  __shared__ int sm[256];
  int t = threadIdx.x;
  const int* T; int* Bb; int nb;
  if (blockIdx.x == 0) { T = T1; Bb = Bb1; nb = NBK1; }
  else { T = T2; Bb = Bb2; nb = NBK2; }
  int v = (t < nb) ? T[t] : 0;
  sm[t] = v;
  __syncthreads();
#pragma unroll
  for (int off = 1; off < 256; off <<= 1) {
    int u = (t >= off) ? sm[t - off] : 0;
    __syncthreads();
    sm[t] += u;
    __syncthreads();
  }
  if (t < nb) Bb[t] = sm[t] - v;
}

__global__ __launch_bounds__(256) void csr_place(
    const int* __restrict__ src1, const int* __restrict__ dst1,
    const int* __restrict__ src2, const int* __restrict__ dst2,
    const int* __restrict__ H1, const int* __restrict__ H2,
    const int* __restrict__ Bb1, const int* __restrict__ Bb2,
    uint32_t* __restrict__ pairs1, uint32_t* __restrict__ pairs2) {
  __shared__ int curs[256];
  int g = blockIdx.x, t = threadIdx.x;
  const int* src; const int* dst; const int* H; const int* Bb;
  uint32_t* pairs; int E, nb, chunk;
  if (g < G1) { src = src1; dst = dst1; H = H1; Bb = Bb1; pairs = pairs1;
                E = CE1; nb = NBK1; chunk = CHUNK1; }
  else { g -= G1; src = src2; dst = dst2; H = H2; Bb = Bb2; pairs = pairs2;
         E = CE2; nb = NBK2; chunk = CHUNK2; }
  if (t < nb) curs[t] = Bb[t] + H[g * nb + t];
  __syncthreads();
  int e0 = g * chunk, e1 = min(e0 + chunk, E);
  for (int e = e0 + t; e < e1; e += 256) {
    int d = dst[e];
    int b = d >> 9;
    int p = atomicAdd(&curs[b], 1);
    pairs[p] = (uint32_t)src[e] | ((uint32_t)(d & 511) << 18);
  }
}

// ---- FUSED bdeg + scan_local ----
__global__ __launch_bounds__(256) void csr_bdeg_scan(
    const uint32_t* __restrict__ pairs1, const uint32_t* __restrict__ pairs2,
    const int* __restrict__ Bb1, const int* __restrict__ Bb2,
    const int* __restrict__ T1, const int* __restrict__ T2,
    int* __restrict__ deg1, int* __restrict__ deg2,
    int* __restrict__ R1, int* __restrict__ R2,
    int* __restrict__ part1, int* __restrict__ part2) {
  __shared__ int cnt[512];
  __shared__ int sm[256];
  int b = blockIdx.x, t = threadIdx.x;
  const uint32_t* pairs; const int* Bb; const int* T;
  int* deg; int* R; int* part; int ndst;
  if (b < NBK1) { pairs = pairs1; Bb = Bb1; T = T1; deg = deg1; R = R1;
                  part = part1; ndst = CN1; }
  else { b -= NBK1; pairs = pairs2; Bb = Bb2; T = T2; deg = deg2; R = R2;
         part = part2; ndst = CN2; }
  cnt[t] = 0;
  cnt[t + 256] = 0;
  __syncthreads();
  int s0 = Bb[b], n = T[b];
  for (int i = t; i < n; i += 256) atomicAdd(&cnt[pairs[s0 + i] >> 18], 1);
  __syncthreads();
  int d0 = b << 9;
  int a = cnt[2 * t], c = cnt[2 * t + 1];
  int i0 = d0 + 2 * t, i1 = d0 + 2 * t + 1;
  if (i0 < ndst) deg[i0] = a;
  if (i1 < ndst) deg[i1] = c;
  int s = a + c;
  sm[t] = s;
  __syncthreads();
#pragma unroll
  for (int off = 1; off < 256; off <<= 1) {
    int u = (t >= off) ? sm[t - off] : 0;
    __syncthreads();
    sm[t] += u;
    __syncthreads();
  }
  int excl = sm[t] - s;
  if (i0 < ndst) R[i0] = excl;
  if (i1 < ndst) R[i1] = excl + a;
  if (t == 255) part[b] = sm[255];
}

__global__ __launch_bounds__(256) void csr_scan_part(
    int* __restrict__ part1, int* __restrict__ part2) {
  __shared__ int sm[256];
  int t = threadIdx.x;
  int* part; int B;
  if (blockIdx.x == 0) { part = part1; B = NBK1; }
  else { part = part2; B = NBK2; }
  int v = (t < B) ? part[t] : 0;
  sm[t] = v;
  __syncthreads();
#pragma unroll
  for (int off = 1; off < 256; off <<= 1) {
    int u = (t >= off) ? sm[t - off] : 0;
    __syncthreads();
    sm[t] += u;
    __syncthreads();
  }
  if (t < B) part[t] = sm[t] - v;
}

// bplace with addback folded in: final offset = R[dd] + part[bucket]
__global__ __launch_bounds__(256) void csr_bplace(
    const uint32_t* __restrict__ pairs1, const uint32_t* __restrict__ pairs2,
    const int* __restrict__ Bb1, const int* __restrict__ Bb2,
    const int* __restrict__ T1, const int* __restrict__ T2,
    const int* __restrict__ R1, const int* __restrict__ R2,
    const int* __restrict__ part1, const int* __restrict__ part2,
    int* __restrict__ esrc1, int* __restrict__ esrc2) {
  __shared__ int curs[512];
  int b = blockIdx.x, t = threadIdx.x;
  const uint32_t* pairs; const int* Bb; const int* T; const int* R;
  const int* part; int* esrc; int ndst;
  if (b < NBK1) { pairs = pairs1; Bb = Bb1; T = T1; R = R1; part = part1;
                  esrc = esrc1; ndst = CN1; }
  else { b -= NBK1; pairs = pairs2; Bb = Bb2; T = T2; R = R2; part = part2;
         esrc = esrc2; ndst = CN2; }
  int d0 = b << 9;
  int pb = part[b];
#pragma unroll
  for (int j = 0; j < 2; ++j) {
    int dd = d0 + t + j * 256;
    curs[t + j * 256] = (dd < ndst) ? R[dd] + pb : 0;
  }
  __syncthreads();
  int s0 = Bb[b], n = T[b];
  for (int i = t; i < n; i += 256) {
    uint32_t pk = pairs[s0 + i];
    int p = atomicAdd(&curs[pk >> 18], 1);
    esrc[p] = (int)(pk & 0x3FFFFu);
  }
}

// ------- gather-mean layer 1 (fp8 rows, 128B): one dst per WAVE,
// 16 lanes/row x uint2 (8 fp8), 4 edge-subgroups, 16-edge main loop -------
__global__ __launch_bounds__(256) void sage_gather1(
    const uint32_t* __restrict__ xf8, const int* __restrict__ esrc,
    const int* __restrict__ R, const int* __restrict__ part,
    const int* __restrict__ deg, uint16_t* __restrict__ agg) {
  const int d = __builtin_amdgcn_readfirstlane(blockIdx.x * 4 + (threadIdx.x >> 6));
  const int lane = threadIdx.x & 63;
  const int cc = lane & 15;    // 8-byte chunk within row (cols 8cc..8cc+7)
  const int h = lane >> 4;     // 0..3 edge subgroup
  const int start = __builtin_amdgcn_readfirstlane(R[d] + part[d >> 9]);
  const int n = __builtin_amdgcn_readfirstlane(deg[d]);
  const uint2* xw = reinterpret_cast<const uint2*>(xf8);   // row = 16 uint2
  float a0 = 0.f, a1 = 0.f, a2 = 0.f, a3 = 0.f;
  float a4 = 0.f, a5 = 0.f, a6 = 0.f, a7 = 0.f;
  float c0 = 0.f, c1 = 0.f, c2 = 0.f, c3 = 0.f;
  float c4 = 0.f, c5 = 0.f, c6 = 0.f, c7 = 0.f;
  int i = 0;
  for (; i + 16 <= n; i += 16) {
    int s0 = esrc[start + i + h];
    int s1 = esrc[start + i + 4 + h];
    int s2 = esrc[start + i + 8 + h];
    int s3 = esrc[start + i + 12 + h];
    uint2 v0 = xw[(uint32_t)s0 * 16u + cc];
    uint2 v1 = xw[(uint32_t)s1 * 16u + cc];
    uint2 v2 = xw[(uint32_t)s2 * 16u + cc];
    uint2 v3 = xw[(uint32_t)s3 * 16u + cc];
    fp8x4_acc(v0.x, a0, a1, a2, a3);
    fp8x4_acc(v0.y, a4, a5, a6, a7);
    fp8x4_acc(v1.x, a0, a1, a2, a3);
    fp8x4_acc(v1.y, a4, a5, a6, a7);
    fp8x4_acc(v2.x, c0, c1, c2, c3);
    fp8x4_acc(v2.y, c4, c5, c6, c7);
    fp8x4_acc(v3.x, c0, c1, c2, c3);
    fp8x4_acc(v3.y, c4, c5, c6, c7);
  }
  for (; i + 4 <= n; i += 4) {
    int s0 = esrc[start + i + h];
    uint2 v = xw[(uint32_t)s0 * 16u + cc];
    fp8x4_acc(v.x, a0, a1, a2, a3);
    fp8x4_acc(v.y, a4, a5, a6, a7);
  }
  if (i < n && h < n - i) {
    int s0 = esrc[start + i + h];
    uint2 v = xw[(uint32_t)s0 * 16u + cc];
    fp8x4_acc(v.x, a0, a1, a2, a3);
    fp8x4_acc(v.y, a4, a5, a6, a7);
  }
  a0 += c0; a1 += c1; a2 += c2; a3 += c3;
  a4 += c4; a5 += c5; a6 += c6; a7 += c7;
  // reduce across the 4 subgroups (lanes 16 and 32 apart)
  a0 += __shfl_xor(a0, 16); a0 += __shfl_xor(a0, 32);
  a1 += __shfl_xor(a1, 16); a1 += __shfl_xor(a1, 32);
  a2 += __shfl_xor(a2, 16); a2 += __shfl_xor(a2, 32);
  a3 += __shfl_xor(a3, 16); a3 += __shfl_xor(a3, 32);
  a4 += __shfl_xor(a4, 16); a4 += __shfl_xor(a4, 32);
  a5 += __shfl_xor(a5, 16); a5 += __shfl_xor(a5, 32);
  a6 += __shfl_xor(a6, 16); a6 += __shfl_xor(a6, 32);
  a7 += __shfl_xor(a7, 16); a7 += __shfl_xor(a7, 32);
  if (lane < 16) {
    float inv = 1.0f / fmaxf((float)n, 1.0f);
    uint4 o;
    o.x = (uint32_t)f2bf(a0 * inv) | ((uint32_t)f2bf(a1 * inv) << 16);
    o.y = (uint32_t)f2bf(a2 * inv) | ((uint32_t)f2bf(a3 * inv) << 16);
    o.z = (uint32_t)f2bf(a4 * inv) | ((uint32_t)f2bf(a5 * inv) << 16);
    o.w = (uint32_t)f2bf(a6 * inv) | ((uint32_t)f2bf(a7 * inv) << 16);
    reinterpret_cast<uint4*>(agg)[(size_t)d * 16 + cc] = o;
  }
}

// ------- FUSED gather-mean layer 2 + log_softmax finalize -------
__global__ __launch_bounds__(256) void sage_gather2_fin(
    const uint16_t* __restrict__ t2, const int* __restrict__ esrc,
    const int* __restrict__ R, const int* __restrict__ part,
    const int* __restrict__ deg, const float* __restrict__ b2,
    float* __restrict__ out) {
  int d = blockIdx.x * 8 + (threadIdx.x >> 5);
  int c = threadIdx.x & 31;
  if (d >= CN2) return;
  int start = R[d] + part[d >> 9], n = deg[d];
  const uint32_t* tw = reinterpret_cast<const uint32_t*>(t2);
  float a0 = 0.f, a1 = 0.f, b0 = 0.f, b1 = 0.f;
  int i = 0;
  for (; i + 8 <= n; i += 8) {
    int s0 = esrc[start + i + 0], s1 = esrc[start + i + 1];
    int s2 = esrc[start + i + 2], s3 = esrc[start + i + 3];
    int s4 = esrc[start + i + 4], s5 = esrc[start + i + 5];
    int s6 = esrc[start + i + 6], s7 = esrc[start + i + 7];
    uint32_t v0 = tw[(size_t)s0 * 32 + c], v1 = tw[(size_t)s1 * 32 + c];
    uint32_t v2 = tw[(size_t)s2 * 32 + c], v3 = tw[(size_t)s3 * 32 + c];
    uint32_t v4 = tw[(size_t)s4 * 32 + c], v5 = tw[(size_t)s5 * 32 + c];
    uint32_t v6 = tw[(size_t)s6 * 32 + c], v7 = tw[(size_t)s7 * 32 + c];
    a0 += (blo(v0) + blo(v1)) + (blo(v2) + blo(v3));
    b0 += (blo(v4) + blo(v5)) + (blo(v6) + blo(v7));
    a1 += (bhi(v0) + bhi(v1)) + (bhi(v2) + bhi(v3));
    b1 += (bhi(v4) + bhi(v5)) + (bhi(v6) + bhi(v7));
  }
  for (; i + 2 <= n; i += 2) {
    int s0 = esrc[start + i + 0], s1 = esrc[start + i + 1];
    uint32_t v0 = tw[(size_t)s0 * 32 + c], v1 = tw[(size_t)s1 * 32 + c];
    a0 += blo(v0) + blo(v1);
    a1 += bhi(v0) + bhi(v1);
  }
  if (i < n) {
    uint32_t v = tw[(size_t)esrc[start + i] * 32 + c];
    a0 += blo(v);
    a1 += bhi(v);
  }
  a0 += b0; a1 += b1;
  float inv = 1.0f / fmaxf((float)n, 1.0f);

  float2 ov = reinterpret_cast<const float2*>(out)[(size_t)d * 32 + c];
  float2 bb = reinterpret_cast<const float2*>(b2)[c];
  float v0 = ov.x + a0 * inv + bb.x;
  float v1 = ov.y + a1 * inv + bb.y;
  float m = fmaxf(v0, v1);
#pragma unroll
  for (int off = 16; off > 0; off >>= 1) m = fmaxf(m, __shfl_xor(m, off));
  float s = expf(v0 - m) + expf(v1 - m);
#pragma unroll
  for (int off = 16; off > 0; off >>= 1) s += __shfl_xor(s, off);
  float lg = logf(s);
  float2 r;
  r.x = v0 - m - lg;
  r.y = v1 - m - lg;
  reinterpret_cast<float2*>(out)[(size_t)d * 32 + c] = r;
}

// ---------------- MEGA kernel (R18: fixed fp8-dequant direct path) ----------------
__global__ __launch_bounds__(256, 2) void sage_mega(
    const uint16_t* __restrict__ agg, const uint32_t* __restrict__ xf8,
    const uint16_t* __restrict__ wfragG, const uint16_t* __restrict__ w2fragG,
    const float* __restrict__ bias, uint16_t* __restrict__ t2,
    float* __restrict__ outp) {
  __shared__ uint16_t wfrag[32768];       // 64 KB: 64 chunks x 512 shorts
  __shared__ uint16_t h1t[4 * 32 * 40];   // 10240 B; per-wave 32x40 transpose tile
  const int tid = threadIdx.x;
  const int w = tid >> 6;
  const int lane = tid & 63;
  const int lcol = lane & 31;             // A-row / B-col / C-col
  const int hi = lane >> 5;               // k-half (frags) / row +4 (C)
  const int row0 = blockIdx.x * 128 + w * 32;
  uint16_t* hw = &h1t[w * (32 * 40)];

  // A fragments: 16 k-tiles of K=16 from [agg (bf16) | x (fp8 dequant)]
  int arow = row0 + lcol;
  arow = arow < CN1 ? arow : CN1 - 1;
  bf16x8 afr[16];
#pragma unroll
  for (int t = 0; t < 8; ++t) {
    afr[t] = *reinterpret_cast<const bf16x8*>(
        agg + (size_t)arow * CD_IN + t * 16 + hi * 8);
  }
#pragma unroll
  for (int t = 8; t < 16; ++t) {
    const int koff = t * 16 - 128;        // fp8 element offset in row (mult of 16)
    // lane needs elements koff + hi*8 .. +7 -> uint2 index = koff/8 + hi
    uint2 v = reinterpret_cast<const uint2*>(xf8)[
        (uint32_t)arow * 16u + (uint32_t)(koff >> 3) + (uint32_t)hi];
    afr[t] = fp8x8_to_bf16x8(v);
  }

  const bool do_out = (row0 < CN2);       // CN2 % 32 == 0 -> wave-uniform
  bf16x8 a2[16];                          // h1 A-frags, filled per n (static idx)

#pragma unroll
  for (int h = 0; h < 2; ++h) {
    // stage half h of W1 fragments: 64 chunks x 1 KB, 16 per wave, coalesced
#pragma unroll
    for (int i = 0; i < 16; ++i) {
      int cc = i * 4 + w;
      int4 v = *reinterpret_cast<const int4*>(
          wfragG + (size_t)(h * 64 + cc) * 512 + lane * 8);
      *reinterpret_cast<int4*>(&wfrag[cc * 512 + lane * 8]) = v;
    }
    __syncthreads();
#pragma unroll
    for (int nn = 0; nn < 4; ++nn) {
      const int n = h * 4 + nn;
      const float bb = bias[n * 32 + lcol];
      f32x16 p0 = (f32x16)0.0f, p1 = (f32x16)0.0f;
#pragma unroll
      for (int t = 0; t < 16; t += 2) {
        bf16x8 b0 = *reinterpret_cast<const bf16x8*>(
            &wfrag[((nn * 16 + t) * 64 + lane) * 8]);
        bf16x8 b1 = *reinterpret_cast<const bf16x8*>(
            &wfrag[((nn * 16 + t + 1) * 64 + lane) * 8]);
        p0 = __builtin_amdgcn_mfma_f32_32x32x16_bf16(afr[t], b0, p0, 0, 0, 0);
        p1 = __builtin_amdgcn_mfma_f32_32x32x16_bf16(afr[t + 1], b1, p1, 0, 0, 0);
      }
      // bias + relu -> bf16 -> per-wave LDS transpose tile (C layout m74/m101)
#pragma unroll
      for (int r = 0; r < 16; ++r) {
        float v = fmaxf(p0[r] + p1[r] + bb, 0.0f);
        int R = (r & 3) + 8 * (r >> 2) + 4 * hi;
        hw[R * 40 + lcol] = f2bf(v);
      }
      // read back as phase-2 A-frags (k = n*32 + {0..15, 16..31})
      a2[n * 2 + 0] = *reinterpret_cast<const bf16x8*>(&hw[lcol * 40 + hi * 8]);
      a2[n * 2 + 1] = *reinterpret_cast<const bf16x8*>(&hw[lcol * 40 + 16 + hi * 8]);
    }
    __syncthreads();   // all waves done reading this half before overwrite
  }

  // stage w2 fragments (64 KB) into the same buffer
#pragma unroll
  for (int i = 0; i < 16; ++i) {
    int cc = i * 4 + w;
    int4 v = *reinterpret_cast<const int4*>(
        w2fragG + (size_t)cc * 512 + lane * 8);
    *reinterpret_cast<int4*>(&wfrag[cc * 512 + lane * 8]) = v;
  }
  __syncthreads();

  // ---- phase 2: jp=0 -> t2 cols (j=0,1); jp=1 -> out cols (j=2,3) ----
#pragma unroll
  for (int jp = 0; jp < 2; ++jp) {
    if (jp == 1 && !do_out) break;
    const int jA = jp * 2, jB = jp * 2 + 1;
    f32x16 aA = (f32x16)0.0f, aB = (f32x16)0.0f;
#pragma unroll
    for (int s = 0; s < 8; ++s) {
      bf16x8 c0A = *reinterpret_cast<const bf16x8*>(
          &wfrag[((jA * 16 + s * 2) * 64 + lane) * 8]);
      bf16x8 c1A = *reinterpret_cast<const bf16x8*>(
          &wfrag[((jA * 16 + s * 2 + 1) * 64 + lane) * 8]);
      bf16x8 c0B = *reinterpret_cast<const bf16x8*>(
          &wfrag[((jB * 16 + s * 2) * 64 + lane) * 8]);
      bf16x8 c1B = *reinterpret_cast<const bf16x8*>(
          &wfrag[((jB * 16 + s * 2 + 1) * 64 + lane) * 8]);
      aA = __builtin_amdgcn_mfma_f32_32x32x16_bf16(a2[s * 2], c0A, aA, 0, 0, 0);
      aB = __builtin_amdgcn_mfma_f32_32x32x16_bf16(a2[s * 2], c0B, aB, 0, 0, 0);
      aA = __builtin_amdgcn_mfma_f32_32x32x16_bf16(a2[s * 2 + 1], c1A, aA, 0, 0, 0);
      aB = __builtin_amdgcn_mfma_f32_32x32x16_bf16(a2[s * 2 + 1], c1B, aB, 0, 0, 0);
    }
    if (jp == 0) {
#pragma unroll
      for (int r = 0; r < 16; ++r) {
        int R = (r & 3) + 8 * (r >> 2) + 4 * hi;
        int rg = row0 + R;
        if (rg < CN1) {
          t2[(size_t)rg * 64 + lcol] = f2bf(aA[r]);
          t2[(size_t)rg * 64 + 32 + lcol] = f2bf(aB[r]);
        }
      }
    } else {
#pragma unroll
      for (int r = 0; r < 16; ++r) {
        int R = (r & 3) + 8 * (r >> 2) + 4 * hi;
        int rg = row0 + R;
        outp[(size_t)rg * 64 + lcol] = aA[r];
        outp[(size_t)rg * 64 + 32 + lcol] = aB[r];
      }
    }
  }
}

extern "C" void kernel_launch(void* const* d_in, const int* in_sizes, int n_in,
                              void* d_out, int out_size, void* d_ws, size_t ws_size,
                              hipStream_t stream) {
  const float* x    = (const float*)d_in[0];
  const int* src1   = (const int*)d_in[1];
  const int* dst1   = (const int*)d_in[2];
  const int* src2   = (const int*)d_in[3];
  const int* dst2   = (const int*)d_in[4];
  const float* W_l1 = (const float*)d_in[5];
  const float* b_l1 = (const float*)d_in[6];
  const float* W_r1 = (const float*)d_in[7];
  const float* W_l2 = (const float*)d_in[8];
  const float* b_l2 = (const float*)d_in[9];
  const float* W_r2 = (const float*)d_in[10];
  float* out = (float*)d_out;
  char* base = (char*)d_ws;

  // ---- workspace layout (bytes), ~73 MB, lifetime-aliased ----
  // [0, 25.6M)       x_fp8 [N0][128] e4m3      (cvt -> gather1, mega)
  // [25.6M, 38.4M)   t2_bf [N1][64] bf16       (mega -> g2fin)
  // [38.4M, 64.0M)   agg_bf [N1][128] bf16     (gather1 -> mega)
  //                    pairs1 aliases [38.4M, 44.8M); pairs2 [44.8M, 46.08M)
  // [64.0M, ...]     CSR ints + weight frags
  uint32_t* x_fp8 = (uint32_t*)base;
  uint16_t* t2_bf = (uint16_t*)(base + 25600000);
  uint16_t* agg_bf= (uint16_t*)(base + 38400000);
  uint32_t* pairs1= (uint32_t*)(base + 38400000);          // alias (dead before gather1)
  uint32_t* pairs2= (uint32_t*)(base + 44800000);          // alias
  int* deg1 = (int*)(base + 64000000);                     // 400 KB
  int* R1   = (int*)(base + 64400000);                     // 400 KB
  int* esrc1= (int*)(base + 64800000);                     // 6.4 MB
  int* deg2 = (int*)(base + 71200000);                     // 80 KB
  int* R2   = (int*)(base + 71280000);                     // 80 KB
  int* esrc2= (int*)(base + 71360000);                     // 1.28 MB
  int* H1   = (int*)(base + 72640000);                     // 200,704 B
  int* H2   = (int*)(base + 72840704);                     // 10,240 B
  char* misc = base + 72850944;
  int* T1  = (int*)(misc);
  int* Bb1 = (int*)(misc + 1024);
  int* T2  = (int*)(misc + 2048);
  int* Bb2 = (int*)(misc + 3072);
  int* part1 = (int*)(misc + 4096);
  int* part2 = (int*)(misc + 5120);
  uint16_t* wfragG  = (uint16_t*)(misc + 6144);            // 128 KB (frag order)
  uint16_t* w2fragG = wfragG + 65536;                      // 64 KB (frag order)

  if (ws_size < 74000000u) return;

  // ---- fused convert (fp8 only) + weight frags + csr_count ----
  cvt_count<<<12868, 256, 0, stream>>>(x, W_l1, W_r1, W_l2, W_r2, dst1, dst2,
                                       x_fp8, wfragG, w2fragG, H1, H2);

  // ---- dual-layer CSR build ----
  csr_scan<<<NBK1 + NBK2, 256, 0, stream>>>(H1, H2, T1, T2);
  csr_base<<<2, 256, 0, stream>>>(T1, T2, Bb1, Bb2);
  csr_place<<<G1 + G2, 256, 0, stream>>>(src1, dst1, src2, dst2, H1, H2,
                                         Bb1, Bb2, pairs1, pairs2);
  csr_bdeg_scan<<<NBK1 + NBK2, 256, 0, stream>>>(pairs1, pairs2, Bb1, Bb2,
                                                 T1, T2, deg1, deg2, R1, R2,
                                                 part1, part2);
  csr_scan_part<<<2, 256, 0, stream>>>(part1, part2);
  csr_bplace<<<NBK1 + NBK2, 256, 0, stream>>>(pairs1, pairs2, Bb1, Bb2, T1, T2,
                                              R1, R2, part1, part2, esrc1, esrc2);

  // ---- gather1 (fp8) -> mega (fp8 direct path) -> fused gather2+finalize ----
  sage_gather1<<<(CN1 + 3) / 4, 256, 0, stream>>>(x_fp8, esrc1, R1, part1, deg1, agg_bf);
  sage_mega<<<(CN1 + 127) / 128, 256, 0, stream>>>(
      agg_bf, x_fp8, wfragG, w2fragG, b_l1, t2_bf, out);
  sage_gather2_fin<<<(CN2 + 7) / 8, 256, 0, stream>>>(
      t2_bf, esrc2, R2, part2, deg2, b_l2, out);
}

// Round 19
// 169.763 us; speedup vs baseline: 1.1580x; 1.0221x over previous
//
#include <hip/hip_runtime.h>
#include <hip/hip_fp8.h>
#include <stdint.h>

// SAGE_876173328847: 2-layer bipartite SAGEConv (mean agg) + log_softmax.
// N0=200000, N1=100000, N2=20000, E1=1.6M, E2=320K, D_IN=128, D_H=256, D_OUT=64.
//
// R1: atomic scatter -> CSR build + gather (3309 -> 667 us).
// R2/R3: bf16 + MFMA (-> 547). R4: fused mega, h1 in LDS (-> 472).
// R7: scan-based multi-split CSR, zero global atomics (-> 366).
// R8: spill-free mega (-> 347). R9: launch fusion (-> 285).
// R11: 32x32x16 fused mega (-> 264). R12: fragment-order W (-> 212).
// R13-15: gather tuning; line-service-bound (-> ~192).
// R16: fp8 e4m3 gather path (-> 180). R17/18: mega fp8 direct path (-> 173.5).
// R19: CSR chain 6 -> 4 launches. Identity: part[b] == T[b] (both = edges in
//      bucket b), so esrc bucket base == pairs bucket base == prefix(T).
//      csr_place computes Bb via local LDS scan of T; bdeg_scan/bplace compute
//      their own s0 via tree reduction; bplace absolutizes R (gathers drop part).

#define CN0 200000
#define CN1 100000
#define CN2 20000
#define CE1 1600000
#define CE2 320000
#define CD_IN 128
#define CD_H 256
#define CD_OUT 64

// multi-split geometry: bucket = dst >> 9 (512 dsts per bucket)
#define NBK1 196          // ceil(N1/512)
#define NBK2 40           // ceil(N2/512)
#define G1 256
#define G2 64
#define CHUNK1 6250       // E1 / G1
#define CHUNK2 5000       // E2 / G2

typedef __bf16 bf16x8 __attribute__((ext_vector_type(8)));
typedef float f32x2 __attribute__((ext_vector_type(2)));
typedef float f32x4 __attribute__((ext_vector_type(4)));
typedef float f32x16 __attribute__((ext_vector_type(16)));
typedef uint16_t u16x4 __attribute__((ext_vector_type(4)));

__device__ inline uint16_t f2bf(float f) {
  uint32_t u = __float_as_uint(f);
  return (uint16_t)((u + 0x7fffu + ((u >> 16) & 1u)) >> 16);
}
__device__ inline float blo(uint32_t v) { return __uint_as_float(v << 16); }
__device__ inline float bhi(uint32_t v) { return __uint_as_float(v & 0xffff0000u); }

// ---- fp8 (OCP e4m3) helpers ----
__device__ inline uint32_t f32x4_to_fp8x4(float a, float b, float c, float d) {
#if __has_builtin(__builtin_amdgcn_cvt_pk_fp8_f32)
  uint32_t pk = (uint32_t)__builtin_amdgcn_cvt_pk_fp8_f32(a, b, 0, false);
  pk = (uint32_t)__builtin_amdgcn_cvt_pk_fp8_f32(c, d, (int)pk, true);
  return pk;
#else
  __hip_fp8_e4m3 e0(a), e1(b), e2(c), e3(d);
  return (uint32_t)e0.__x | ((uint32_t)e1.__x << 8) |
         ((uint32_t)e2.__x << 16) | ((uint32_t)e3.__x << 24);
#endif
}

__device__ inline float fp8_one(uint32_t b) {   // fallback scalar decode
  uint32_t s = (b >> 7) & 1u, e = (b >> 3) & 15u, m = b & 7u;
  float f = (e == 0) ? (float)m * 0.001953125f
                     : __uint_as_float(((e + 120u) << 23) | (m << 20));
  return s ? -f : f;
}

__device__ inline void fp8x4_dec(uint32_t w, float& p0, float& p1,
                                 float& p2, float& p3) {
#if __has_builtin(__builtin_amdgcn_cvt_pk_f32_fp8)
  f32x2 lo = __builtin_amdgcn_cvt_pk_f32_fp8(w, false);
  f32x2 hi = __builtin_amdgcn_cvt_pk_f32_fp8(w, true);
  p0 = lo[0]; p1 = lo[1]; p2 = hi[0]; p3 = hi[1];
#else
  p0 = fp8_one(w & 0xffu);
  p1 = fp8_one((w >> 8) & 0xffu);
  p2 = fp8_one((w >> 16) & 0xffu);
  p3 = fp8_one((w >> 24) & 0xffu);
#endif
}

__device__ inline void fp8x4_acc(uint32_t w, float& p0, float& p1,
                                 float& p2, float& p3) {
  float q0, q1, q2, q3;
  fp8x4_dec(w, q0, q1, q2, q3);
  p0 += q0; p1 += q1; p2 += q2; p3 += q3;
}

__device__ inline bf16x8 fp8x8_to_bf16x8(uint2 v) {
  float f[8];
  fp8x4_dec(v.x, f[0], f[1], f[2], f[3]);
  fp8x4_dec(v.y, f[4], f[5], f[6], f[7]);
  uint16_t o[8];
#pragma unroll
  for (int e = 0; e < 8; ++e) o[e] = f2bf(f[e]);
  return *reinterpret_cast<bf16x8*>(o);
}

// ---- fused: x->fp8 (12500 blk) + weight frags (48) + csr_count (320) ----
__global__ __launch_bounds__(256) void cvt_count(
    const float* __restrict__ x, const float* __restrict__ Wl1,
    const float* __restrict__ Wr1, const float* __restrict__ Wl2,
    const float* __restrict__ Wr2, const int* __restrict__ dst1,
    const int* __restrict__ dst2, uint32_t* __restrict__ x_fp8,
    uint16_t* __restrict__ wfragG, uint16_t* __restrict__ w2fragG,
    int* __restrict__ H1, int* __restrict__ H2) {
  __shared__ int hist[256];
  int blk = blockIdx.x;
  if (blk < 12500) {
    int i = blk * 256 + threadIdx.x;      // < 3,200,000 (each = 2 float4s)
    const float4* xp = reinterpret_cast<const float4*>(x);
    float4 v0 = xp[2 * i];
    float4 v1 = xp[2 * i + 1];
    uint2 o;
    o.x = f32x4_to_fp8x4(v0.x, v0.y, v0.z, v0.w);
    o.y = f32x4_to_fp8x4(v1.x, v1.y, v1.z, v1.w);
    reinterpret_cast<uint2*>(x_fp8)[i] = o;
    return;
  }
  if (blk < 12548) {
    int c = (blk - 12500) * 256 + threadIdx.x;   // 0..12287
    uint16_t o[8];
    if (c < 8192) {
      int lane = c & 63, t = (c >> 6) & 15, n = c >> 10;
      int row = n * 32 + (lane & 31);
      int kk = t * 16 + (lane >> 5) * 8;
      const float* srcp = (kk < 128) ? (Wl1 + (size_t)row * 128 + kk)
                                     : (Wr1 + (size_t)row * 128 + (kk - 128));
#pragma unroll
      for (int e = 0; e < 8; ++e) o[e] = f2bf(srcp[e]);
      *reinterpret_cast<int4*>(wfragG + (size_t)c * 8) = *reinterpret_cast<int4*>(o);
    } else {
      int cc = c - 8192;                    // 0..4095
      int lane = cc & 63, tt = (cc >> 6) & 15, j = cc >> 10;
      int row = j * 32 + (lane & 31);
      int kk = tt * 16 + (lane >> 5) * 8;
      const float* srcp = (row < 64) ? (Wl2 + (size_t)row * 256 + kk)
                                     : (Wr2 + (size_t)(row - 64) * 256 + kk);
#pragma unroll
      for (int e = 0; e < 8; ++e) o[e] = f2bf(srcp[e]);
      *reinterpret_cast<int4*>(w2fragG + (size_t)cc * 8) = *reinterpret_cast<int4*>(o);
    }
    return;
  }
  // ---- histogram chunk ----
  int g = blk - 12548, t = threadIdx.x;
  const int* dst; int* H; int E, nb, chunk;
  if (g < G1) { dst = dst1; H = H1; E = CE1; nb = NBK1; chunk = CHUNK1; }
  else { g -= G1; dst = dst2; H = H2; E = CE2; nb = NBK2; chunk = CHUNK2; }
  hist[t] = 0;
  __syncthreads();
  int e0 = g * chunk, e1 = min(e0 + chunk, E);
  for (int e = e0 + t; e < e1; e += 256) atomicAdd(&hist[dst[e] >> 9], 1);
  __syncthreads();
  if (t < nb) H[g * nb + t] = hist[t];
}

// ---------------- dual-layer scan-based multi-split ----------------
// per-bucket scan over chunks; totals -> T.
__global__ __launch_bounds__(256) void csr_scan(
    int* __restrict__ H1, int* __restrict__ H2,
    int* __restrict__ T1, int* __restrict__ T2) {
  __shared__ int sm[256];
  int b = blockIdx.x, t = threadIdx.x;
  int* H; int* T; int nb, G;
  if (b < NBK1) { H = H1; T = T1; nb = NBK1; G = G1; }
  else { b -= NBK1; H = H2; T = T2; nb = NBK2; G = G2; }
  int v = (t < G) ? H[t * nb + b] : 0;
  sm[t] = v;
  __syncthreads();
#pragma unroll
  for (int off = 1; off < 256; off <<= 1) {
    int u = (t >= off) ? sm[t - off] : 0;
    __syncthreads();
    sm[t] += u;
    __syncthreads();
  }
  if (t < G) H[t * nb + b] = sm[t] - v;  // exclusive over chunks
  if (t == 255) T[b] = sm[255];          // bucket total (= edges in bucket)
}

// place: Bb computed per-block via local LDS scan of T (csr_base eliminated)
__global__ __launch_bounds__(256) void csr_place(
    const int* __restrict__ src1, const int* __restrict__ dst1,
    const int* __restrict__ src2, const int* __restrict__ dst2,
    const int* __restrict__ H1, const int* __restrict__ H2,
    const int* __restrict__ T1, const int* __restrict__ T2,
    uint32_t* __restrict__ pairs1, uint32_t* __restrict__ pairs2) {
  __shared__ int curs[256];
  __shared__ int sm[256];
  int g = blockIdx.x, t = threadIdx.x;
  const int* src; const int* dst; const int* H; const int* T;
  uint32_t* pairs; int E, nb, chunk;
  if (g < G1) { src = src1; dst = dst1; H = H1; T = T1; pairs = pairs1;
                E = CE1; nb = NBK1; chunk = CHUNK1; }
  else { g -= G1; src = src2; dst = dst2; H = H2; T = T2; pairs = pairs2;
         E = CE2; nb = NBK2; chunk = CHUNK2; }
  // local inclusive scan of T -> exclusive Bb
  int v = (t < nb) ? T[t] : 0;
  sm[t] = v;
  __syncthreads();
#pragma unroll
  for (int off = 1; off < 256; off <<= 1) {
    int u = (t >= off) ? sm[t - off] : 0;
    __syncthreads();
    sm[t] += u;
    __syncthreads();
  }
  if (t < nb) curs[t] = (sm[t] - v) + H[g * nb + t];
  __syncthreads();
  int e0 = g * chunk, e1 = min(e0 + chunk, E);
  for (int e = e0 + t; e < e1; e += 256) {
    int d = dst[e];
    int b = d >> 9;
    int p = atomicAdd(&curs[b], 1);
    pairs[p] = (uint32_t)src[e] | ((uint32_t)(d & 511) << 18);
  }
}

// bdeg+scan: s0 (bucket base) via tree reduction over T; writes deg + R (local)
__global__ __launch_bounds__(256) void csr_bdeg_scan(
    const uint32_t* __restrict__ pairs1, const uint32_t* __restrict__ pairs2,
    const int* __restrict__ T1, const int* __restrict__ T2,
    int* __restrict__ deg1, int* __restrict__ deg2,
    int* __restrict__ R1, int* __restrict__ R2) {
  __shared__ int cnt[512];
  __shared__ int sm[256];
  int b = blockIdx.x, t = threadIdx.x;
  const uint32_t* pairs; const int* T;
  int* deg; int* R; int ndst;
  if (b < NBK1) { pairs = pairs1; T = T1; deg = deg1; R = R1; ndst = CN1; }
  else { b -= NBK1; pairs = pairs2; T = T2; deg = deg2; R = R2; ndst = CN2; }
  // s0 = sum T[j<b]
  cnt[t] = 0;
  cnt[t + 256] = 0;
  sm[t] = (t < b) ? T[t] : 0;
  __syncthreads();
#pragma unroll
  for (int off = 128; off > 0; off >>= 1) {
    if (t < off) sm[t] += sm[t + off];
    __syncthreads();
  }
  int s0 = sm[0];
  int n = T[b];
  __syncthreads();   // everyone has s0; sm free for reuse
  for (int i = t; i < n; i += 256) atomicAdd(&cnt[pairs[s0 + i] >> 18], 1);
  __syncthreads();
  int d0 = b << 9;
  int a = cnt[2 * t], c = cnt[2 * t + 1];
  int i0 = d0 + 2 * t, i1 = d0 + 2 * t + 1;
  if (i0 < ndst) deg[i0] = a;
  if (i1 < ndst) deg[i1] = c;
  int s = a + c;
  sm[t] = s;
  __syncthreads();
#pragma unroll
  for (int off = 1; off < 256; off <<= 1) {
    int u = (t >= off) ? sm[t - off] : 0;
    __syncthreads();
    sm[t] += u;
    __syncthreads();
  }
  int excl = sm[t] - s;
  if (i0 < ndst) R[i0] = excl;
  if (i1 < ndst) R[i1] = excl + a;
}

// bplace: s0 via reduction over T (== esrc bucket base since part[b]==T[b]);
// absolutizes R (R[dd] += s0) so gathers need no part lookup.
__global__ __launch_bounds__(256) void csr_bplace(
    const uint32_t* __restrict__ pairs1, const uint32_t* __restrict__ pairs2,
    const int* __restrict__ T1, const int* __restrict__ T2,
    int* __restrict__ R1, int* __restrict__ R2,
    int* __restrict__ esrc1, int* __restrict__ esrc2) {
  __shared__ int cnt[512];
  __shared__ int sm[256];
  int b = blockIdx.x, t = threadIdx.x;
  const uint32_t* pairs; const int* T;
  int* R; int* esrc; int ndst;
  if (b < NBK1) { pairs = pairs1; T = T1; R = R1; esrc = esrc1; ndst = CN1; }
  else { b -= NBK1; pairs = pairs2; T = T2; R = R2; esrc = esrc2; ndst = CN2; }
  sm[t] = (t < b) ? T[t] : 0;
  __syncthreads();
#pragma unroll
  for (int off = 128; off > 0; off >>= 1) {
    if (t < off) sm[t] += sm[t + off];
    __syncthreads();
  }
  int s0 = sm[0];          // bucket base: same for pairs and esrc
  int n = T[b];
  __syncthreads();
  int d0 = b << 9;
#pragma unroll
  for (int j = 0; j < 2; ++j) {
    int dd = d0 + t + j * 256;
    if (dd < ndst) {
      int r = R[dd] + s0;
      cnt[t + j * 256] = r;
      R[dd] = r;           // absolutize for the gathers
    } else {
      cnt[t + j * 256] = 0;
    }
  }
  __syncthreads();
  for (int i = t; i < n; i += 256) {
    uint32_t pk = pairs[s0 + i];
    int p = atomicAdd(&cnt[pk >> 18], 1);
    esrc[p] = (int)(pk & 0x3FFFFu);
  }
}

// ------- gather-mean layer 1 (fp8 rows, 128B): one dst per WAVE,
// 16 lanes/row x uint2 (8 fp8), 4 edge-subgroups, 16-edge main loop -------
__global__ __launch_bounds__(256) void sage_gather1(
    const uint32_t* __restrict__ xf8, const int* __restrict__ esrc,
    const int* __restrict__ R, const int* __restrict__ deg,
    uint16_t* __restrict__ agg) {
  const int d = __builtin_amdgcn_readfirstlane(blockIdx.x * 4 + (threadIdx.x >> 6));
  const int lane = threadIdx.x & 63;
  const int cc = lane & 15;    // 8-byte chunk within row (cols 8cc..8cc+7)
  const int h = lane >> 4;     // 0..3 edge subgroup
  const int start = __builtin_amdgcn_readfirstlane(R[d]);
  const int n = __builtin_amdgcn_readfirstlane(deg[d]);
  const uint2* xw = reinterpret_cast<const uint2*>(xf8);   // row = 16 uint2
  float a0 = 0.f, a1 = 0.f, a2 = 0.f, a3 = 0.f;
  float a4 = 0.f, a5 = 0.f, a6 = 0.f, a7 = 0.f;
  float c0 = 0.f, c1 = 0.f, c2 = 0.f, c3 = 0.f;
  float c4 = 0.f, c5 = 0.f, c6 = 0.f, c7 = 0.f;
  int i = 0;
  for (; i + 16 <= n; i += 16) {
    int s0 = esrc[start + i + h];
    int s1 = esrc[start + i + 4 + h];
    int s2 = esrc[start + i + 8 + h];
    int s3 = esrc[start + i + 12 + h];
    uint2 v0 = xw[(uint32_t)s0 * 16u + cc];
    uint2 v1 = xw[(uint32_t)s1 * 16u + cc];
    uint2 v2 = xw[(uint32_t)s2 * 16u + cc];
    uint2 v3 = xw[(uint32_t)s3 * 16u + cc];
    fp8x4_acc(v0.x, a0, a1, a2, a3);
    fp8x4_acc(v0.y, a4, a5, a6, a7);
    fp8x4_acc(v1.x, a0, a1, a2, a3);
    fp8x4_acc(v1.y, a4, a5, a6, a7);
    fp8x4_acc(v2.x, c0, c1, c2, c3);
    fp8x4_acc(v2.y, c4, c5, c6, c7);
    fp8x4_acc(v3.x, c0, c1, c2, c3);
    fp8x4_acc(v3.y, c4, c5, c6, c7);
  }
  for (; i + 4 <= n; i += 4) {
    int s0 = esrc[start + i + h];
    uint2 v = xw[(uint32_t)s0 * 16u + cc];
    fp8x4_acc(v.x, a0, a1, a2, a3);
    fp8x4_acc(v.y, a4, a5, a6, a7);
  }
  if (i < n && h < n - i) {
    int s0 = esrc[start + i + h];
    uint2 v = xw[(uint32_t)s0 * 16u + cc];
    fp8x4_acc(v.x, a0, a1, a2, a3);
    fp8x4_acc(v.y, a4, a5, a6, a7);
  }
  a0 += c0; a1 += c1; a2 += c2; a3 += c3;
  a4 += c4; a5 += c5; a6 += c6; a7 += c7;
  // reduce across the 4 subgroups (lanes 16 and 32 apart)
  a0 += __shfl_xor(a0, 16); a0 += __shfl_xor(a0, 32);
  a1 += __shfl_xor(a1, 16); a1 += __shfl_xor(a1, 32);
  a2 += __shfl_xor(a2, 16); a2 += __shfl_xor(a2, 32);
  a3 += __shfl_xor(a3, 16); a3 += __shfl_xor(a3, 32);
  a4 += __shfl_xor(a4, 16); a4 += __shfl_xor(a4, 32);
  a5 += __shfl_xor(a5, 16); a5 += __shfl_xor(a5, 32);
  a6 += __shfl_xor(a6, 16); a6 += __shfl_xor(a6, 32);
  a7 += __shfl_xor(a7, 16); a7 += __shfl_xor(a7, 32);
  if (lane < 16) {
    float inv = 1.0f / fmaxf((float)n, 1.0f);
    uint4 o;
    o.x = (uint32_t)f2bf(a0 * inv) | ((uint32_t)f2bf(a1 * inv) << 16);
    o.y = (uint32_t)f2bf(a2 * inv) | ((uint32_t)f2bf(a3 * inv) << 16);
    o.z = (uint32_t)f2bf(a4 * inv) | ((uint32_t)f2bf(a5 * inv) << 16);
    o.w = (uint32_t)f2bf(a6 * inv) | ((uint32_t)f2bf(a7 * inv) << 16);
    reinterpret_cast<uint4*>(agg)[(size_t)d * 16 + cc] = o;
  }
}

// ------- FUSED gather-mean layer 2 + log_softmax finalize -------
__global__ __launch_bounds__(256) void sage_gather2_fin(
    const uint16_t* __restrict__ t2, const int* __restrict__ esrc,
    const int* __restrict__ R, const int* __restrict__ deg,
    const float* __restrict__ b2, float* __restrict__ out) {
  int d = blockIdx.x * 8 + (threadIdx.x >> 5);
  int c = threadIdx.x & 31;
  if (d >= CN2) return;
  int start = R[d], n = deg[d];
  const uint32_t* tw = reinterpret_cast<const uint32_t*>(t2);
  float a0 = 0.f, a1 = 0.f, b0 = 0.f, b1 = 0.f;
  int i = 0;
  for (; i + 8 <= n; i += 8) {
    int s0 = esrc[start + i + 0], s1 = esrc[start + i + 1];
    int s2 = esrc[start + i + 2], s3 = esrc[start + i + 3];
    int s4 = esrc[start + i + 4], s5 = esrc[start + i + 5];
    int s6 = esrc[start + i + 6], s7 = esrc[start + i + 7];
    uint32_t v0 = tw[(size_t)s0 * 32 + c], v1 = tw[(size_t)s1 * 32 + c];
    uint32_t v2 = tw[(size_t)s2 * 32 + c], v3 = tw[(size_t)s3 * 32 + c];
    uint32_t v4 = tw[(size_t)s4 * 32 + c], v5 = tw[(size_t)s5 * 32 + c];
    uint32_t v6 = tw[(size_t)s6 * 32 + c], v7 = tw[(size_t)s7 * 32 + c];
    a0 += (blo(v0) + blo(v1)) + (blo(v2) + blo(v3));
    b0 += (blo(v4) + blo(v5)) + (blo(v6) + blo(v7));
    a1 += (bhi(v0) + bhi(v1)) + (bhi(v2) + bhi(v3));
    b1 += (bhi(v4) + bhi(v5)) + (bhi(v6) + bhi(v7));
  }
  for (; i + 2 <= n; i += 2) {
    int s0 = esrc[start + i + 0], s1 = esrc[start + i + 1];
    uint32_t v0 = tw[(size_t)s0 * 32 + c], v1 = tw[(size_t)s1 * 32 + c];
    a0 += blo(v0) + blo(v1);
    a1 += bhi(v0) + bhi(v1);
  }
  if (i < n) {
    uint32_t v = tw[(size_t)esrc[start + i] * 32 + c];
    a0 += blo(v);
    a1 += bhi(v);
  }
  a0 += b0; a1 += b1;
  float inv = 1.0f / fmaxf((float)n, 1.0f);

  float2 ov = reinterpret_cast<const float2*>(out)[(size_t)d * 32 + c];
  float2 bb = reinterpret_cast<const float2*>(b2)[c];
  float v0 = ov.x + a0 * inv + bb.x;
  float v1 = ov.y + a1 * inv + bb.y;
  float m = fmaxf(v0, v1);
#pragma unroll
  for (int off = 16; off > 0; off >>= 1) m = fmaxf(m, __shfl_xor(m, off));
  float s = expf(v0 - m) + expf(v1 - m);
#pragma unroll
  for (int off = 16; off > 0; off >>= 1) s += __shfl_xor(s, off);
  float lg = logf(s);
  float2 r;
  r.x = v0 - m - lg;
  r.y = v1 - m - lg;
  reinterpret_cast<float2*>(out)[(size_t)d * 32 + c] = r;
}

// ---------------- MEGA kernel (fp8-dequant direct path) ----------------
__global__ __launch_bounds__(256, 2) void sage_mega(
    const uint16_t* __restrict__ agg, const uint32_t* __restrict__ xf8,
    const uint16_t* __restrict__ wfragG, const uint16_t* __restrict__ w2fragG,
    const float* __restrict__ bias, uint16_t* __restrict__ t2,
    float* __restrict__ outp) {
  __shared__ uint16_t wfrag[32768];       // 64 KB: 64 chunks x 512 shorts
  __shared__ uint16_t h1t[4 * 32 * 40];   // 10240 B; per-wave 32x40 transpose tile
  const int tid = threadIdx.x;
  const int w = tid >> 6;
  const int lane = tid & 63;
  const int lcol = lane & 31;             // A-row / B-col / C-col
  const int hi = lane >> 5;               // k-half (frags) / row +4 (C)
  const int row0 = blockIdx.x * 128 + w * 32;
  uint16_t* hw = &h1t[w * (32 * 40)];

  // A fragments: 16 k-tiles of K=16 from [agg (bf16) | x (fp8 dequant)]
  int arow = row0 + lcol;
  arow = arow < CN1 ? arow : CN1 - 1;
  bf16x8 afr[16];
#pragma unroll
  for (int t = 0; t < 8; ++t) {
    afr[t] = *reinterpret_cast<const bf16x8*>(
        agg + (size_t)arow * CD_IN + t * 16 + hi * 8);
  }
#pragma unroll
  for (int t = 8; t < 16; ++t) {
    const int koff = t * 16 - 128;        // fp8 element offset in row (mult of 16)
    uint2 v = reinterpret_cast<const uint2*>(xf8)[
        (uint32_t)arow * 16u + (uint32_t)(koff >> 3) + (uint32_t)hi];
    afr[t] = fp8x8_to_bf16x8(v);
  }

  const bool do_out = (row0 < CN2);       // CN2 % 32 == 0 -> wave-uniform
  bf16x8 a2[16];                          // h1 A-frags, filled per n (static idx)

#pragma unroll
  for (int h = 0; h < 2; ++h) {
    // stage half h of W1 fragments: 64 chunks x 1 KB, 16 per wave, coalesced
#pragma unroll
    for (int i = 0; i < 16; ++i) {
      int cc = i * 4 + w;
      int4 v = *reinterpret_cast<const int4*>(
          wfragG + (size_t)(h * 64 + cc) * 512 + lane * 8);
      *reinterpret_cast<int4*>(&wfrag[cc * 512 + lane * 8]) = v;
    }
    __syncthreads();
#pragma unroll
    for (int nn = 0; nn < 4; ++nn) {
      const int n = h * 4 + nn;
      const float bb = bias[n * 32 + lcol];
      f32x16 p0 = (f32x16)0.0f, p1 = (f32x16)0.0f;
#pragma unroll
      for (int t = 0; t < 16; t += 2) {
        bf16x8 b0 = *reinterpret_cast<const bf16x8*>(
            &wfrag[((nn * 16 + t) * 64 + lane) * 8]);
        bf16x8 b1 = *reinterpret_cast<const bf16x8*>(
            &wfrag[((nn * 16 + t + 1) * 64 + lane) * 8]);
        p0 = __builtin_amdgcn_mfma_f32_32x32x16_bf16(afr[t], b0, p0, 0, 0, 0);
        p1 = __builtin_amdgcn_mfma_f32_32x32x16_bf16(afr[t + 1], b1, p1, 0, 0, 0);
      }
      // bias + relu -> bf16 -> per-wave LDS transpose tile (C layout m74/m101)
#pragma unroll
      for (int r = 0; r < 16; ++r) {
        float v = fmaxf(p0[r] + p1[r] + bb, 0.0f);
        int R = (r & 3) + 8 * (r >> 2) + 4 * hi;
        hw[R * 40 + lcol] = f2bf(v);
      }
      // read back as phase-2 A-frags (k = n*32 + {0..15, 16..31})
      a2[n * 2 + 0] = *reinterpret_cast<const bf16x8*>(&hw[lcol * 40 + hi * 8]);
      a2[n * 2 + 1] = *reinterpret_cast<const bf16x8*>(&hw[lcol * 40 + 16 + hi * 8]);
    }
    __syncthreads();   // all waves done reading this half before overwrite
  }

  // stage w2 fragments (64 KB) into the same buffer
#pragma unroll
  for (int i = 0; i < 16; ++i) {
    int cc = i * 4 + w;
    int4 v = *reinterpret_cast<const int4*>(
        w2fragG + (size_t)cc * 512 + lane * 8);
    *reinterpret_cast<int4*>(&wfrag[cc * 512 + lane * 8]) = v;
  }
  __syncthreads();

  // ---- phase 2: jp=0 -> t2 cols (j=0,1); jp=1 -> out cols (j=2,3) ----
#pragma unroll
  for (int jp = 0; jp < 2; ++jp) {
    if (jp == 1 && !do_out) break;
    const int jA = jp * 2, jB = jp * 2 + 1;
    f32x16 aA = (f32x16)0.0f, aB = (f32x16)0.0f;
#pragma unroll
    for (int s = 0; s < 8; ++s) {
      bf16x8 c0A = *reinterpret_cast<const bf16x8*>(
          &wfrag[((jA * 16 + s * 2) * 64 + lane) * 8]);
      bf16x8 c1A = *reinterpret_cast<const bf16x8*>(
          &wfrag[((jA * 16 + s * 2 + 1) * 64 + lane) * 8]);
      bf16x8 c0B = *reinterpret_cast<const bf16x8*>(
          &wfrag[((jB * 16 + s * 2) * 64 + lane) * 8]);
      bf16x8 c1B = *reinterpret_cast<const bf16x8*>(
          &wfrag[((jB * 16 + s * 2 + 1) * 64 + lane) * 8]);
      aA = __builtin_amdgcn_mfma_f32_32x32x16_bf16(a2[s * 2], c0A, aA, 0, 0, 0);
      aB = __builtin_amdgcn_mfma_f32_32x32x16_bf16(a2[s * 2], c0B, aB, 0, 0, 0);
      aA = __builtin_amdgcn_mfma_f32_32x32x16_bf16(a2[s * 2 + 1], c1A, aA, 0, 0, 0);
      aB = __builtin_amdgcn_mfma_f32_32x32x16_bf16(a2[s * 2 + 1], c1B, aB, 0, 0, 0);
    }
    if (jp == 0) {
#pragma unroll
      for (int r = 0; r < 16; ++r) {
        int R = (r & 3) + 8 * (r >> 2) + 4 * hi;
        int rg = row0 + R;
        if (rg < CN1) {
          t2[(size_t)rg * 64 + lcol] = f2bf(aA[r]);
          t2[(size_t)rg * 64 + 32 + lcol] = f2bf(aB[r]);
        }
      }
    } else {
#pragma unroll
      for (int r = 0; r < 16; ++r) {
        int R = (r & 3) + 8 * (r >> 2) + 4 * hi;
        int rg = row0 + R;
        outp[(size_t)rg * 64 + lcol] = aA[r];
        outp[(size_t)rg * 64 + 32 + lcol] = aB[r];
      }
    }
  }
}

extern "C" void kernel_launch(void* const* d_in, const int* in_sizes, int n_in,
                              void* d_out, int out_size, void* d_ws, size_t ws_size,
                              hipStream_t stream) {
  const float* x    = (const float*)d_in[0];
  const int* src1   = (const int*)d_in[1];
  const int* dst1   = (const int*)d_in[2];
  const int* src2   = (const int*)d_in[3];
  const int* dst2   = (const int*)d_in[4];
  const float* W_l1 = (const float*)d_in[5];
  const float* b_l1 = (const float*)d_in[6];
  const float* W_r1 = (const float*)d_in[7];
  const float* W_l2 = (const float*)d_in[8];
  const float* b_l2 = (const float*)d_in[9];
  const float* W_r2 = (const float*)d_in[10];
  float* out = (float*)d_out;
  char* base = (char*)d_ws;

  // ---- workspace layout (bytes), ~73 MB, lifetime-aliased ----
  // [0, 25.6M)       x_fp8 [N0][128] e4m3      (cvt -> gather1, mega)
  // [25.6M, 38.4M)   t2_bf [N1][64] bf16       (mega -> g2fin)
  // [38.4M, 64.0M)   agg_bf [N1][128] bf16     (gather1 -> mega)
  //                    pairs1 aliases [38.4M, 44.8M); pairs2 [44.8M, 46.08M)
  // [64.0M, ...]     CSR ints + weight frags
  uint32_t* x_fp8 = (uint32_t*)base;
  uint16_t* t2_bf = (uint16_t*)(base + 25600000);
  uint16_t* agg_bf= (uint16_t*)(base + 38400000);
  uint32_t* pairs1= (uint32_t*)(base + 38400000);          // alias (dead before gather1)
  uint32_t* pairs2= (uint32_t*)(base + 44800000);          // alias
  int* deg1 = (int*)(base + 64000000);                     // 400 KB
  int* R1   = (int*)(base + 64400000);                     // 400 KB
  int* esrc1= (int*)(base + 64800000);                     // 6.4 MB
  int* deg2 = (int*)(base + 71200000);                     // 80 KB
  int* R2   = (int*)(base + 71280000);                     // 80 KB
  int* esrc2= (int*)(base + 71360000);                     // 1.28 MB
  int* H1   = (int*)(base + 72640000);                     // 200,704 B
  int* H2   = (int*)(base + 72840704);                     // 10,240 B
  char* misc = base + 72850944;
  int* T1  = (int*)(misc);
  int* T2  = (int*)(misc + 2048);
  uint16_t* wfragG  = (uint16_t*)(misc + 6144);            // 128 KB (frag order)
  uint16_t* w2fragG = wfragG + 65536;                      // 64 KB (frag order)

  if (ws_size < 74000000u) return;

  // ---- fused convert (fp8 only) + weight frags + csr_count ----
  cvt_count<<<12868, 256, 0, stream>>>(x, W_l1, W_r1, W_l2, W_r2, dst1, dst2,
                                       x_fp8, wfragG, w2fragG, H1, H2);

  // ---- dual-layer CSR build (4 launches) ----
  csr_scan<<<NBK1 + NBK2, 256, 0, stream>>>(H1, H2, T1, T2);
  csr_place<<<G1 + G2, 256, 0, stream>>>(src1, dst1, src2, dst2, H1, H2,
                                         T1, T2, pairs1, pairs2);
  csr_bdeg_scan<<<NBK1 + NBK2, 256, 0, stream>>>(pairs1, pairs2, T1, T2,
                                                 deg1, deg2, R1, R2);
  csr_bplace<<<NBK1 + NBK2, 256, 0, stream>>>(pairs1, pairs2, T1, T2,
                                              R1, R2, esrc1, esrc2);

  // ---- gather1 (fp8) -> mega (fp8 direct path) -> fused gather2+finalize ----
  sage_gather1<<<(CN1 + 3) / 4, 256, 0, stream>>>(x_fp8, esrc1, R1, deg1, agg_bf);
  sage_mega<<<(CN1 + 127) / 128, 256, 0, stream>>>(
      agg_bf, x_fp8, wfragG, w2fragG, b_l1, t2_bf, out);
  sage_gather2_fin<<<(CN2 + 7) / 8, 256, 0, stream>>>(
      t2_bf, esrc2, R2, deg2, b_l2, out);
}